// Round 6
// baseline (10557.009 us; speedup 1.0000x reference)
//
#include <hip/hip_runtime.h>
#include <hip/hip_bf16.h>

// LFQ argmax, round 6: 3-term split-bf16 MFMA (round-4-proven numerics:
// score ~= xh*ch + xh*cl + xl*ch, err sigma ~3e-5) in the round-5 code-split
// grid (2048 blocks, XCD-affine 8-way split -> L2-resident slices).
// Top-2 per split via j-packed scores (fmed3/fmax, 2 VALU/score); combine
// exactly rescores all candidates within MARGIN of approx max.
// Output float32[16385] (indices + loss 0).
#define NT 16384
#define ND 128
#define NC 16384
#define NSPLIT 8
#define MARGIN 0.02f   // >300 sigma of (split error + packing error)

typedef __bf16 bf16x8 __attribute__((ext_vector_type(8)));
typedef unsigned short u16x8 __attribute__((ext_vector_type(8)));
typedef float f32x4 __attribute__((ext_vector_type(4)));

static __device__ __forceinline__ unsigned short f2bf(float f) {
    __hip_bfloat16 h = __float2bfloat16(f);   // RNE
    return *(unsigned short*)&h;
}
static __device__ __forceinline__ float bf2f(unsigned short u) {
    __hip_bfloat16 h = *(__hip_bfloat16*)&u;
    return __bfloat162float(h);
}
static __device__ __forceinline__ bf16x8 u2b(u16x8 u) {
    bf16x8 b; __builtin_memcpy(&b, &u, 16); return b;
}

// ---------------- codebook fp32 -> bf16 hi/lo split ----------------
__global__ __launch_bounds__(512) void lfq_convert_cb(
    const float4* __restrict__ cb4, ushort4* __restrict__ ch, ushort4* __restrict__ cl)
{
    const unsigned i = blockIdx.x * 512 + threadIdx.x;   // 0..524287
    float4 v = cb4[i];
    ushort4 h, l;
    h.x = f2bf(v.x); l.x = f2bf(v.x - bf2f(h.x));
    h.y = f2bf(v.y); l.y = f2bf(v.y - bf2f(h.y));
    h.z = f2bf(v.z); l.z = f2bf(v.z - bf2f(h.z));
    h.w = f2bf(v.w); l.w = f2bf(v.w - bf2f(h.w));
    ch[i] = h; cl[i] = l;
}

// round-3/4-validated exact fp32 dot
static __device__ __forceinline__ float exact_dot(
    const float4* __restrict__ xr4, const float* __restrict__ cf, int cidx)
{
    const float4* cr = (const float4*)(cf + (size_t)cidx * ND);
    float a0 = 0.f, a1 = 0.f, a2 = 0.f, a3 = 0.f;
#pragma unroll
    for (int i = 0; i < 32; i += 4) {
        float4 x0 = xr4[i+0], x1 = xr4[i+1], x2 = xr4[i+2], x3 = xr4[i+3];
        float4 c0 = cr[i+0],  c1 = cr[i+1],  c2 = cr[i+2],  c3 = cr[i+3];
        a0 += x0.x*c0.x + x0.y*c0.y + x0.z*c0.z + x0.w*c0.w;
        a1 += x1.x*c1.x + x1.y*c1.y + x1.z*c1.z + x1.w*c1.w;
        a2 += x2.x*c2.x + x2.y*c2.y + x2.z*c2.z + x2.w*c2.w;
        a3 += x3.x*c3.x + x3.y*c3.y + x3.z*c3.z + x3.w*c3.w;
    }
    return (a0 + a1) + (a2 + a3);
}

// ------------- stage 1: grid 2048 = 256 token-blocks x 8 splits -------------
// Block: 64 tokens x 2048-code slice, 8 waves; wave: g=w>>2 (2 token-tiles),
// q=w&3 (code tiles j*4+q, j=0..31).
__global__ __launch_bounds__(512, 2) void lfq_stage1(
    const float* __restrict__ xf,
    const unsigned short* __restrict__ ch, const unsigned short* __restrict__ cl,
    float* __restrict__ sb1, float* __restrict__ sb2,
    int* __restrict__ si1, int* __restrict__ si2)
{
    const int split = blockIdx.x & 7;
    const int tb    = blockIdx.x >> 3;
    const int t0    = tb * 64;
    const int tid   = threadIdx.x;
    const int w     = tid >> 6;
    const int lane  = tid & 63;
    const int n     = lane & 15;
    const int quad  = lane >> 4;
    const int g     = w >> 2;
    const int q     = w & 3;

    // A fragments: fp32 x -> bf16 hi/lo in-register. A[m=n][k=quad*8+j].
    bf16x8 ah[2][4], al[2][4];
#pragma unroll
    for (int tt = 0; tt < 2; ++tt) {
        const float* xr = xf + (size_t)(t0 + g * 32 + tt * 16 + n) * ND + quad * 8;
#pragma unroll
        for (int kk = 0; kk < 4; ++kk) {
            float tmp[8];
            *(float4*)(tmp)     = *(const float4*)(xr + kk * 32);
            *(float4*)(tmp + 4) = *(const float4*)(xr + kk * 32 + 4);
            u16x8 hu, lu;
#pragma unroll
            for (int e = 0; e < 8; ++e) {
                unsigned short h = f2bf(tmp[e]);
                hu[e] = h;
                lu[e] = f2bf(tmp[e] - bf2f(h));
            }
            ah[tt][kk] = u2b(hu);
            al[tt][kk] = u2b(lu);
        }
    }

    // j-packed top-2 per accumulator lane-slot (low 5 mantissa bits = 31-j)
    float b1[2][4], b2[2][4];
#pragma unroll
    for (int tt = 0; tt < 2; ++tt)
#pragma unroll
        for (int r = 0; r < 4; ++r) { b1[tt][r] = -3.0e38f; b2[tt][r] = -3.0e38f; }

    const int cb_base = split * (NC / NSPLIT);   // 2048-code slice
    const size_t bofs = (size_t)(cb_base + q * 16 + n) * ND + quad * 8;
    const unsigned short* pBh = ch + bofs;
    const unsigned short* pBl = cl + bofs;

    bf16x8 Bh[2][4], Bl[2][4];
#pragma unroll
    for (int kk = 0; kk < 4; ++kk) {
        Bh[0][kk] = *(const bf16x8*)(pBh + kk * 32);
        Bl[0][kk] = *(const bf16x8*)(pBl + kk * 32);
    }

    for (int j = 0; j < 32; ++j) {
        const int cur = j & 1, nxt = cur ^ 1;
        if (j < 31) {
            const unsigned short* p1h = pBh + (size_t)(j + 1) * (64 * ND);
            const unsigned short* p1l = pBl + (size_t)(j + 1) * (64 * ND);
#pragma unroll
            for (int kk = 0; kk < 4; ++kk) {
                Bh[nxt][kk] = *(const bf16x8*)(p1h + kk * 32);
                Bl[nxt][kk] = *(const bf16x8*)(p1l + kk * 32);
            }
        }
        const unsigned pk = (unsigned)(31 - j);   // wave-uniform; bigger = smaller code
#pragma unroll
        for (int tt = 0; tt < 2; ++tt) {
            f32x4 acc = {0.f, 0.f, 0.f, 0.f};
#pragma unroll
            for (int kk = 0; kk < 4; ++kk) {
                acc = __builtin_amdgcn_mfma_f32_16x16x32_bf16(ah[tt][kk], Bh[cur][kk], acc, 0, 0, 0);
                acc = __builtin_amdgcn_mfma_f32_16x16x32_bf16(ah[tt][kk], Bl[cur][kk], acc, 0, 0, 0);
                acc = __builtin_amdgcn_mfma_f32_16x16x32_bf16(al[tt][kk], Bh[cur][kk], acc, 0, 0, 0);
            }
#pragma unroll
            for (int r = 0; r < 4; ++r) {
                float p = __uint_as_float((__float_as_uint(acc[r]) & 0xFFFFFFE0u) | pk);
                b2[tt][r] = __builtin_amdgcn_fmed3f(p, b1[tt][r], b2[tt][r]); // new 2nd (old b1!)
                b1[tt][r] = fmaxf(p, b1[tt][r]);
            }
        }
    }

    // unpack (score, code) and cross-lane top-2 merge over 16 code-lanes
    float v1[2][4], v2[2][4];
    int   c1[2][4], c2[2][4];
#pragma unroll
    for (int tt = 0; tt < 2; ++tt)
#pragma unroll
        for (int r = 0; r < 4; ++r) {
            int j1 = 31 - (int)(__float_as_uint(b1[tt][r]) & 31u);
            int j2 = 31 - (int)(__float_as_uint(b2[tt][r]) & 31u);
            v1[tt][r] = b1[tt][r]; c1[tt][r] = cb_base + (j1 * 4 + q) * 16 + n;
            v2[tt][r] = b2[tt][r]; c2[tt][r] = cb_base + (j2 * 4 + q) * 16 + n;
        }

#pragma unroll
    for (int tt = 0; tt < 2; ++tt)
#pragma unroll
        for (int r = 0; r < 4; ++r) {
#pragma unroll
            for (int off = 1; off < 16; off <<= 1) {
                float ob1 = __shfl_xor(v1[tt][r], off, 64);
                int   oi1 = __shfl_xor(c1[tt][r], off, 64);
                float ob2 = __shfl_xor(v2[tt][r], off, 64);
                int   oi2 = __shfl_xor(c2[tt][r], off, 64);
                bool gt = (ob1 > v1[tt][r]) ||
                          (ob1 == v1[tt][r] && oi1 < c1[tt][r]);
                float ls = gt ? v1[tt][r] : ob1;    // loser of top-1 duel
                int   li = gt ? c1[tt][r] : oi1;
                float ws_ = gt ? ob2 : v2[tt][r];   // winner's runner-up
                int   wi = gt ? oi2 : c2[tt][r];
                bool s2 = (ls > ws_) || (ls == ws_ && li < wi);
                v2[tt][r] = s2 ? ls : ws_;
                c2[tt][r] = s2 ? li : wi;
                v1[tt][r] = gt ? ob1 : v1[tt][r];
                c1[tt][r] = gt ? oi1 : c1[tt][r];
            }
        }

    __shared__ float lb1[4][64], lb2[4][64];
    __shared__ int   li1[4][64], li2[4][64];
    if (n == 0) {
#pragma unroll
        for (int tt = 0; tt < 2; ++tt)
#pragma unroll
            for (int r = 0; r < 4; ++r) {
                const int tk = g * 32 + tt * 16 + quad * 4 + r;
                lb1[q][tk] = v1[tt][r]; li1[q][tk] = c1[tt][r];
                lb2[q][tk] = v2[tt][r]; li2[q][tk] = c2[tt][r];
            }
    }
    __syncthreads();

    if (tid < 64) {
        float B1 = lb1[0][tid], B2 = lb2[0][tid];
        int   I1 = li1[0][tid], I2 = li2[0][tid];
#pragma unroll
        for (int qq = 1; qq < 4; ++qq) {
            float ob1 = lb1[qq][tid], ob2 = lb2[qq][tid];
            int   oi1 = li1[qq][tid], oi2 = li2[qq][tid];
            bool gt = (ob1 > B1) || (ob1 == B1 && oi1 < I1);
            float ls = gt ? B1 : ob1;  int li = gt ? I1 : oi1;
            float ws_ = gt ? ob2 : B2; int wi = gt ? I2 : oi2;
            bool s2 = (ls > ws_) || (ls == ws_ && li < wi);
            B2 = s2 ? ls : ws_;  I2 = s2 ? li : wi;
            B1 = gt ? ob1 : B1;  I1 = gt ? oi1 : I1;
        }
        const size_t o = (size_t)split * NT + t0 + tid;
        sb1[o] = B1; si1[o] = I1;
        sb2[o] = B2; si2[o] = I2;
    }
}

// ------------- combine: merge 8 splits, exact-rescore margin band -------------
__global__ __launch_bounds__(256) void lfq_combine(
    const float* __restrict__ sb1, const float* __restrict__ sb2,
    const int* __restrict__ si1, const int* __restrict__ si2,
    const float* __restrict__ xf, const float* __restrict__ cf,
    float* __restrict__ out, int out_size)
{
    const int t = blockIdx.x * 256 + threadIdx.x;   // 64 blocks -> 16384

    float v[16]; int id[16];
#pragma unroll
    for (int s = 0; s < NSPLIT; ++s) {
        const size_t o = (size_t)s * NT + t;
        v[2*s]   = sb1[o]; id[2*s]   = si1[o];
        v[2*s+1] = sb2[o]; id[2*s+1] = si2[o];
    }
    float A1 = v[0]; int I1 = id[0];
#pragma unroll
    for (int k = 1; k < 16; ++k)
        if (v[k] > A1 || (v[k] == A1 && id[k] < I1)) { A1 = v[k]; I1 = id[k]; }

    float4 xr4[32];
    const float4* xrow = (const float4*)(xf + (size_t)t * ND);
#pragma unroll
    for (int i = 0; i < 32; ++i) xr4[i] = xrow[i];

    float bs = -__builtin_inff(); int bi = 0; bool have = false;
#pragma unroll
    for (int k = 0; k < 16; ++k) {
        if (v[k] >= A1 - MARGIN) {
            float s = exact_dot(xr4, cf, id[k]);
            if (!have || s > bs || (s == bs && id[k] < bi)) { bs = s; bi = id[k]; have = true; }
        }
    }
    out[t] = (float)bi;
    if (t == 0 && out_size > NT) out[NT] = 0.0f;
}

// ------------- fallback: round-3 exact fp32 kernel (tiny ws) -------------
__global__ __launch_bounds__(512) void lfq_fp32_argmax(
    const float* __restrict__ xf, const float* __restrict__ cf,
    float* __restrict__ out, int out_size)
{
    const int tid = threadIdx.x;
    const int w   = tid >> 6;
    const int tok = tid & 63;
    const int t0  = blockIdx.x * 64;
    __shared__ float s_sc[8][64];
    __shared__ int   s_ix[8][64];

    float4 xr[32];
    const float4* xrow = (const float4*)(xf + (size_t)(t0 + tok) * ND);
#pragma unroll
    for (int i = 0; i < 32; ++i) xr[i] = xrow[i];

    float bs = -__builtin_inff();
    int   bi = 0;
    const int c_begin = w * (NC / 8);
    for (int c = c_begin; c < c_begin + NC / 8; ++c) {
        float s = exact_dot(xr, cf, c);
        if (s > bs) { bs = s; bi = c; }
    }
    s_sc[w][tok] = bs; s_ix[w][tok] = bi;
    __syncthreads();
    if (tid < 64) {
        float bsf = s_sc[0][tid]; int bif = s_ix[0][tid];
#pragma unroll
        for (int ww = 1; ww < 8; ++ww) {
            float s2 = s_sc[ww][tid]; int ii = s_ix[ww][tid];
            if (s2 > bsf || (s2 == bsf && ii < bif)) { bsf = s2; bif = ii; }
        }
        out[t0 + tid] = (float)bif;
    }
    if (blockIdx.x == 0 && tid == 0 && out_size > NT) out[NT] = 0.0f;
}

extern "C" void kernel_launch(void* const* d_in, const int* in_sizes, int n_in,
                              void* d_out, int out_size, void* d_ws, size_t ws_size,
                              hipStream_t stream) {
    const float* x  = (const float*)d_in[0];
    const float* cb = (const float*)d_in[1];
    float* out = (float*)d_out;

    // ws: ch 4.19MB | cl 4.19MB | sb1/sb2/si1/si2 512KB each  -> ~10.5 MB
    const size_t NCE = (size_t)NC * ND;          // 2,097,152 codebook elements
    const size_t NEED = NCE * 2 * 2 + (size_t)NT * NSPLIT * 4 * 4;
    if (ws_size >= NEED) {
        char* ws = (char*)d_ws;
        unsigned short* ch = (unsigned short*)ws;
        unsigned short* cl = (unsigned short*)(ws + NCE * 2);
        char* sp = ws + NCE * 4;
        float* sb1 = (float*)sp;
        float* sb2 = (float*)(sp + (size_t)NT * NSPLIT * 4);
        int*   si1 = (int*)  (sp + (size_t)NT * NSPLIT * 8);
        int*   si2 = (int*)  (sp + (size_t)NT * NSPLIT * 12);

        lfq_convert_cb<<<dim3(1024), dim3(512), 0, stream>>>(
            (const float4*)cb, (ushort4*)ch, (ushort4*)cl);
        lfq_stage1<<<dim3(256 * NSPLIT), dim3(512), 0, stream>>>(
            x, ch, cl, sb1, sb2, si1, si2);
        lfq_combine<<<dim3(64), dim3(256), 0, stream>>>(
            sb1, sb2, si1, si2, x, cb, out, out_size);
    } else {
        lfq_fp32_argmax<<<dim3(NT / 64), dim3(512), 0, stream>>>(x, cb, out, out_size);
    }
}

// Round 7
// 609.272 us; speedup vs baseline: 17.3273x; 17.3273x over previous
//
#include <hip/hip_runtime.h>
#include <hip/hip_bf16.h>

// LFQ argmax, round 7: round-6 design with the scratch-spill fixed.
//  - ROOT CAUSE of round 6's 10.5 ms: j-loop lost "#pragma unroll 2", so
//    Bh[cur][kk] became a dynamically-indexed local array -> scratch memory
//    (WRITE_SIZE 88 MB, MfmaUtil 0.75%). Pragma restored -> cur/nxt constant.
//  - Conversion tmp arrays replaced with pure bit-op f2bf on float4 registers
//    (no address-taken locals anywhere in stage1).
// Numerics (validated round 6, absmax 0): score ~= xh*ch + xh*cl + xl*ch,
// j-packed top-2 (low 5 mantissa bits = 31-j), per-split top-2 in ws,
// combine exactly rescores all candidates within MARGIN of approx max.
// Output float32[16385] (indices + loss 0).
#define NT 16384
#define ND 128
#define NC 16384
#define NSPLIT 8
#define MARGIN 0.02f   // >300 sigma of (split error + packing error)

typedef __bf16 bf16x8 __attribute__((ext_vector_type(8)));
typedef unsigned short u16x8 __attribute__((ext_vector_type(8)));
typedef float f32x4 __attribute__((ext_vector_type(4)));

// RNE fp32->bf16 as pure bit ops (no address-taking, SROA-safe; data is finite)
static __device__ __forceinline__ unsigned short f2bf(float f) {
    unsigned u = __float_as_uint(f);
    return (unsigned short)((u + 0x7FFFu + ((u >> 16) & 1u)) >> 16);
}
static __device__ __forceinline__ float bf2f(unsigned short u) {
    return __uint_as_float(((unsigned)u) << 16);
}
static __device__ __forceinline__ bf16x8 u2b(u16x8 u) {
    return __builtin_bit_cast(bf16x8, u);
}

// ---------------- codebook fp32 -> bf16 hi/lo split ----------------
__global__ __launch_bounds__(512) void lfq_convert_cb(
    const float4* __restrict__ cb4, ushort4* __restrict__ ch, ushort4* __restrict__ cl)
{
    const unsigned i = blockIdx.x * 512 + threadIdx.x;   // 0..524287
    float4 v = cb4[i];
    ushort4 h, l;
    h.x = f2bf(v.x); l.x = f2bf(v.x - bf2f(h.x));
    h.y = f2bf(v.y); l.y = f2bf(v.y - bf2f(h.y));
    h.z = f2bf(v.z); l.z = f2bf(v.z - bf2f(h.z));
    h.w = f2bf(v.w); l.w = f2bf(v.w - bf2f(h.w));
    ch[i] = h; cl[i] = l;
}

// round-3/4-validated exact fp32 dot
static __device__ __forceinline__ float exact_dot(
    const float4* __restrict__ xr4, const float* __restrict__ cf, int cidx)
{
    const float4* cr = (const float4*)(cf + (size_t)cidx * ND);
    float a0 = 0.f, a1 = 0.f, a2 = 0.f, a3 = 0.f;
#pragma unroll
    for (int i = 0; i < 32; i += 4) {
        float4 x0 = xr4[i+0], x1 = xr4[i+1], x2 = xr4[i+2], x3 = xr4[i+3];
        float4 c0 = cr[i+0],  c1 = cr[i+1],  c2 = cr[i+2],  c3 = cr[i+3];
        a0 += x0.x*c0.x + x0.y*c0.y + x0.z*c0.z + x0.w*c0.w;
        a1 += x1.x*c1.x + x1.y*c1.y + x1.z*c1.z + x1.w*c1.w;
        a2 += x2.x*c2.x + x2.y*c2.y + x2.z*c2.z + x2.w*c2.w;
        a3 += x3.x*c3.x + x3.y*c3.y + x3.z*c3.z + x3.w*c3.w;
    }
    return (a0 + a1) + (a2 + a3);
}

// ------------- stage 1: grid 2048 = 256 token-blocks x 8 splits -------------
// split = blockIdx&7 (XCD-affine -> each XCD's L2 holds its 1 MB hi+lo slice).
// Block: 64 tokens x 2048-code slice, 8 waves; wave: g=w>>2 (2 token-tiles),
// q=w&3 (code tiles j*4+q, j=0..31).
__global__ __launch_bounds__(512, 2) void lfq_stage1(
    const float* __restrict__ xf,
    const unsigned short* __restrict__ ch, const unsigned short* __restrict__ cl,
    float* __restrict__ sb1, float* __restrict__ sb2,
    int* __restrict__ si1, int* __restrict__ si2)
{
    const int split = blockIdx.x & 7;
    const int tb    = blockIdx.x >> 3;
    const int t0    = tb * 64;
    const int tid   = threadIdx.x;
    const int w     = tid >> 6;
    const int lane  = tid & 63;
    const int n     = lane & 15;
    const int quad  = lane >> 4;
    const int g     = w >> 2;
    const int q     = w & 3;

    // A fragments: fp32 x -> bf16 hi/lo, all in vector registers.
    bf16x8 ah[2][4], al[2][4];
#pragma unroll
    for (int tt = 0; tt < 2; ++tt) {
        const float* xr = xf + (size_t)(t0 + g * 32 + tt * 16 + n) * ND + quad * 8;
#pragma unroll
        for (int kk = 0; kk < 4; ++kk) {
            float4 v0 = *(const float4*)(xr + kk * 32);
            float4 v1 = *(const float4*)(xr + kk * 32 + 4);
            u16x8 hu, lu;
            hu[0] = f2bf(v0.x); lu[0] = f2bf(v0.x - bf2f(hu[0]));
            hu[1] = f2bf(v0.y); lu[1] = f2bf(v0.y - bf2f(hu[1]));
            hu[2] = f2bf(v0.z); lu[2] = f2bf(v0.z - bf2f(hu[2]));
            hu[3] = f2bf(v0.w); lu[3] = f2bf(v0.w - bf2f(hu[3]));
            hu[4] = f2bf(v1.x); lu[4] = f2bf(v1.x - bf2f(hu[4]));
            hu[5] = f2bf(v1.y); lu[5] = f2bf(v1.y - bf2f(hu[5]));
            hu[6] = f2bf(v1.z); lu[6] = f2bf(v1.z - bf2f(hu[6]));
            hu[7] = f2bf(v1.w); lu[7] = f2bf(v1.w - bf2f(hu[7]));
            ah[tt][kk] = u2b(hu);
            al[tt][kk] = u2b(lu);
        }
    }

    // j-packed top-2 per accumulator slot (low 5 mantissa bits = 31-j)
    float b1[2][4], b2[2][4];
#pragma unroll
    for (int tt = 0; tt < 2; ++tt)
#pragma unroll
        for (int r = 0; r < 4; ++r) { b1[tt][r] = -3.0e38f; b2[tt][r] = -3.0e38f; }

    const int cb_base = split * (NC / NSPLIT);   // 2048-code slice
    const size_t bofs = (size_t)(cb_base + q * 16 + n) * ND + quad * 8;
    const unsigned short* pBh = ch + bofs;
    const unsigned short* pBl = cl + bofs;

    bf16x8 Bh[2][4], Bl[2][4];
#pragma unroll
    for (int kk = 0; kk < 4; ++kk) {
        Bh[0][kk] = *(const bf16x8*)(pBh + kk * 32);
        Bl[0][kk] = *(const bf16x8*)(pBl + kk * 32);
    }

#pragma unroll 2   // CRITICAL: makes cur/nxt compile-time -> B stays in VGPRs
    for (int j = 0; j < 32; ++j) {
        const int cur = j & 1, nxt = cur ^ 1;
        if (j < 31) {
            const unsigned short* p1h = pBh + (size_t)(j + 1) * (64 * ND);
            const unsigned short* p1l = pBl + (size_t)(j + 1) * (64 * ND);
#pragma unroll
            for (int kk = 0; kk < 4; ++kk) {
                Bh[nxt][kk] = *(const bf16x8*)(p1h + kk * 32);
                Bl[nxt][kk] = *(const bf16x8*)(p1l + kk * 32);
            }
        }
        const unsigned pk = (unsigned)(31 - j);   // bigger pk = smaller code
#pragma unroll
        for (int tt = 0; tt < 2; ++tt) {
            f32x4 acc = {0.f, 0.f, 0.f, 0.f};
#pragma unroll
            for (int kk = 0; kk < 4; ++kk) {
                acc = __builtin_amdgcn_mfma_f32_16x16x32_bf16(ah[tt][kk], Bh[cur][kk], acc, 0, 0, 0);
                acc = __builtin_amdgcn_mfma_f32_16x16x32_bf16(ah[tt][kk], Bl[cur][kk], acc, 0, 0, 0);
                acc = __builtin_amdgcn_mfma_f32_16x16x32_bf16(al[tt][kk], Bh[cur][kk], acc, 0, 0, 0);
            }
#pragma unroll
            for (int r = 0; r < 4; ++r) {
                float p = __uint_as_float((__float_as_uint(acc[r]) & 0xFFFFFFE0u) | pk);
                b2[tt][r] = __builtin_amdgcn_fmed3f(p, b1[tt][r], b2[tt][r]); // new 2nd
                b1[tt][r] = fmaxf(p, b1[tt][r]);
            }
        }
    }

    // unpack (score, code) and cross-lane top-2 merge over 16 code-lanes
    float v1[2][4], v2[2][4];
    int   c1[2][4], c2[2][4];
#pragma unroll
    for (int tt = 0; tt < 2; ++tt)
#pragma unroll
        for (int r = 0; r < 4; ++r) {
            int j1 = 31 - (int)(__float_as_uint(b1[tt][r]) & 31u);
            int j2 = 31 - (int)(__float_as_uint(b2[tt][r]) & 31u);
            v1[tt][r] = b1[tt][r]; c1[tt][r] = cb_base + (j1 * 4 + q) * 16 + n;
            v2[tt][r] = b2[tt][r]; c2[tt][r] = cb_base + (j2 * 4 + q) * 16 + n;
        }

#pragma unroll
    for (int tt = 0; tt < 2; ++tt)
#pragma unroll
        for (int r = 0; r < 4; ++r) {
#pragma unroll
            for (int off = 1; off < 16; off <<= 1) {
                float ob1 = __shfl_xor(v1[tt][r], off, 64);
                int   oi1 = __shfl_xor(c1[tt][r], off, 64);
                float ob2 = __shfl_xor(v2[tt][r], off, 64);
                int   oi2 = __shfl_xor(c2[tt][r], off, 64);
                bool gt = (ob1 > v1[tt][r]) ||
                          (ob1 == v1[tt][r] && oi1 < c1[tt][r]);
                float ls = gt ? v1[tt][r] : ob1;    // loser of top-1 duel
                int   li = gt ? c1[tt][r] : oi1;
                float ws_ = gt ? ob2 : v2[tt][r];   // winner's runner-up
                int   wi = gt ? oi2 : c2[tt][r];
                bool s2 = (ls > ws_) || (ls == ws_ && li < wi);
                v2[tt][r] = s2 ? ls : ws_;
                c2[tt][r] = s2 ? li : wi;
                v1[tt][r] = gt ? ob1 : v1[tt][r];
                c1[tt][r] = gt ? oi1 : c1[tt][r];
            }
        }

    __shared__ float lb1[4][64], lb2[4][64];
    __shared__ int   li1[4][64], li2[4][64];
    if (n == 0) {
#pragma unroll
        for (int tt = 0; tt < 2; ++tt)
#pragma unroll
            for (int r = 0; r < 4; ++r) {
                const int tk = g * 32 + tt * 16 + quad * 4 + r;
                lb1[q][tk] = v1[tt][r]; li1[q][tk] = c1[tt][r];
                lb2[q][tk] = v2[tt][r]; li2[q][tk] = c2[tt][r];
            }
    }
    __syncthreads();

    if (tid < 64) {
        float B1 = lb1[0][tid], B2 = lb2[0][tid];
        int   I1 = li1[0][tid], I2 = li2[0][tid];
#pragma unroll
        for (int qq = 1; qq < 4; ++qq) {
            float ob1 = lb1[qq][tid], ob2 = lb2[qq][tid];
            int   oi1 = li1[qq][tid], oi2 = li2[qq][tid];
            bool gt = (ob1 > B1) || (ob1 == B1 && oi1 < I1);
            float ls = gt ? B1 : ob1;  int li = gt ? I1 : oi1;
            float ws_ = gt ? ob2 : B2; int wi = gt ? I2 : oi2;
            bool s2 = (ls > ws_) || (ls == ws_ && li < wi);
            B2 = s2 ? ls : ws_;  I2 = s2 ? li : wi;
            B1 = gt ? ob1 : B1;  I1 = gt ? oi1 : I1;
        }
        const size_t o = (size_t)split * NT + t0 + tid;
        sb1[o] = B1; si1[o] = I1;
        sb2[o] = B2; si2[o] = I2;
    }
}

// ------------- combine: merge 8 splits, exact-rescore margin band -------------
__global__ __launch_bounds__(256) void lfq_combine(
    const float* __restrict__ sb1, const float* __restrict__ sb2,
    const int* __restrict__ si1, const int* __restrict__ si2,
    const float* __restrict__ xf, const float* __restrict__ cf,
    float* __restrict__ out, int out_size)
{
    const int t = blockIdx.x * 256 + threadIdx.x;   // 64 blocks -> 16384

    float v[16]; int id[16];
#pragma unroll
    for (int s = 0; s < NSPLIT; ++s) {
        const size_t o = (size_t)s * NT + t;
        v[2*s]   = sb1[o]; id[2*s]   = si1[o];
        v[2*s+1] = sb2[o]; id[2*s+1] = si2[o];
    }
    float A1 = v[0]; int I1 = id[0];
#pragma unroll
    for (int k = 1; k < 16; ++k)
        if (v[k] > A1 || (v[k] == A1 && id[k] < I1)) { A1 = v[k]; I1 = id[k]; }

    float4 xr4[32];
    const float4* xrow = (const float4*)(xf + (size_t)t * ND);
#pragma unroll
    for (int i = 0; i < 32; ++i) xr4[i] = xrow[i];

    float bs = -__builtin_inff(); int bi = 0; bool have = false;
#pragma unroll
    for (int k = 0; k < 16; ++k) {
        if (v[k] >= A1 - MARGIN) {
            float s = exact_dot(xr4, cf, id[k]);
            if (!have || s > bs || (s == bs && id[k] < bi)) { bs = s; bi = id[k]; have = true; }
        }
    }
    out[t] = (float)bi;
    if (t == 0 && out_size > NT) out[NT] = 0.0f;
}

// ------------- fallback: round-3 exact fp32 kernel (tiny ws) -------------
__global__ __launch_bounds__(512) void lfq_fp32_argmax(
    const float* __restrict__ xf, const float* __restrict__ cf,
    float* __restrict__ out, int out_size)
{
    const int tid = threadIdx.x;
    const int w   = tid >> 6;
    const int tok = tid & 63;
    const int t0  = blockIdx.x * 64;
    __shared__ float s_sc[8][64];
    __shared__ int   s_ix[8][64];

    float4 xr[32];
    const float4* xrow = (const float4*)(xf + (size_t)(t0 + tok) * ND);
#pragma unroll
    for (int i = 0; i < 32; ++i) xr[i] = xrow[i];

    float bs = -__builtin_inff();
    int   bi = 0;
    const int c_begin = w * (NC / 8);
    for (int c = c_begin; c < c_begin + NC / 8; ++c) {
        float s = exact_dot(xr, cf, c);
        if (s > bs) { bs = s; bi = c; }
    }
    s_sc[w][tok] = bs; s_ix[w][tok] = bi;
    __syncthreads();
    if (tid < 64) {
        float bsf = s_sc[0][tid]; int bif = s_ix[0][tid];
#pragma unroll
        for (int ww = 1; ww < 8; ++ww) {
            float s2 = s_sc[ww][tid]; int ii = s_ix[ww][tid];
            if (s2 > bsf || (s2 == bsf && ii < bif)) { bsf = s2; bif = ii; }
        }
        out[t0 + tid] = (float)bif;
    }
    if (blockIdx.x == 0 && tid == 0 && out_size > NT) out[NT] = 0.0f;
}

extern "C" void kernel_launch(void* const* d_in, const int* in_sizes, int n_in,
                              void* d_out, int out_size, void* d_ws, size_t ws_size,
                              hipStream_t stream) {
    const float* x  = (const float*)d_in[0];
    const float* cb = (const float*)d_in[1];
    float* out = (float*)d_out;

    // ws: ch 4.19MB | cl 4.19MB | sb1/sb2/si1/si2 512KB each  -> ~10.5 MB
    const size_t NCE = (size_t)NC * ND;          // 2,097,152 codebook elements
    const size_t NEED = NCE * 2 * 2 + (size_t)NT * NSPLIT * 4 * 4;
    if (ws_size >= NEED) {
        char* ws = (char*)d_ws;
        unsigned short* ch = (unsigned short*)ws;
        unsigned short* cl = (unsigned short*)(ws + NCE * 2);
        char* sp = ws + NCE * 4;
        float* sb1 = (float*)sp;
        float* sb2 = (float*)(sp + (size_t)NT * NSPLIT * 4);
        int*   si1 = (int*)  (sp + (size_t)NT * NSPLIT * 8);
        int*   si2 = (int*)  (sp + (size_t)NT * NSPLIT * 12);

        lfq_convert_cb<<<dim3(1024), dim3(512), 0, stream>>>(
            (const float4*)cb, (ushort4*)ch, (ushort4*)cl);
        lfq_stage1<<<dim3(256 * NSPLIT), dim3(512), 0, stream>>>(
            x, ch, cl, sb1, sb2, si1, si2);
        lfq_combine<<<dim3(64), dim3(256), 0, stream>>>(
            sb1, sb2, si1, si2, x, cb, out, out_size);
    } else {
        lfq_fp32_argmax<<<dim3(NT / 64), dim3(512), 0, stream>>>(x, cb, out, out_size);
    }
}

// Round 8
// 522.404 us; speedup vs baseline: 20.2085x; 1.1663x over previous
//
#include <hip/hip_runtime.h>
#include <hip/hip_bf16.h>

// LFQ argmax, round 8: kill the 2x redundant B-stream and double arithmetic
// intensity. Round-7 counters: MfmaUtil 15.5 / VALU 16.7 / HBM 0.9% ->
// cache-BW bound: both token-groups streamed identical B (4.3 GB @ ~7.8 TB/s).
// Now: wave covers 64 tokens (tt=4), waves split codes 8-way (q=w) -> each
// B byte read once per block (1.05 MB/block, 2.1 GB total) and feeds 48 MFMAs
// per 8-load batch. Numerics unchanged (validated r6/r7): 3-term split-bf16,
// j-packed top-2 (4 low mantissa bits = 15-j), 8-split top-2 + exact rescore
// of the MARGIN band. Output float32[16385].
#define NT 16384
#define ND 128
#define NC 16384
#define NSPLIT 8
#define MARGIN 0.02f   // >100x the (split + packing) comparison error

typedef __bf16 bf16x8 __attribute__((ext_vector_type(8)));
typedef unsigned short u16x8 __attribute__((ext_vector_type(8)));
typedef float f32x4 __attribute__((ext_vector_type(4)));

// RNE fp32->bf16 as pure bit ops (no address-taking; data finite)
static __device__ __forceinline__ unsigned short f2bf(float f) {
    unsigned u = __float_as_uint(f);
    return (unsigned short)((u + 0x7FFFu + ((u >> 16) & 1u)) >> 16);
}
static __device__ __forceinline__ float bf2f(unsigned short u) {
    return __uint_as_float(((unsigned)u) << 16);
}
static __device__ __forceinline__ bf16x8 u2b(u16x8 u) {
    return __builtin_bit_cast(bf16x8, u);
}

// ---------------- codebook fp32 -> bf16 hi/lo split ----------------
__global__ __launch_bounds__(512) void lfq_convert_cb(
    const float4* __restrict__ cb4, ushort4* __restrict__ ch, ushort4* __restrict__ cl)
{
    const unsigned i = blockIdx.x * 512 + threadIdx.x;   // 0..524287
    float4 v = cb4[i];
    ushort4 h, l;
    h.x = f2bf(v.x); l.x = f2bf(v.x - bf2f(h.x));
    h.y = f2bf(v.y); l.y = f2bf(v.y - bf2f(h.y));
    h.z = f2bf(v.z); l.z = f2bf(v.z - bf2f(h.z));
    h.w = f2bf(v.w); l.w = f2bf(v.w - bf2f(h.w));
    ch[i] = h; cl[i] = l;
}

// round-3/4-validated exact fp32 dot
static __device__ __forceinline__ float exact_dot(
    const float4* __restrict__ xr4, const float* __restrict__ cf, int cidx)
{
    const float4* cr = (const float4*)(cf + (size_t)cidx * ND);
    float a0 = 0.f, a1 = 0.f, a2 = 0.f, a3 = 0.f;
#pragma unroll
    for (int i = 0; i < 32; i += 4) {
        float4 x0 = xr4[i+0], x1 = xr4[i+1], x2 = xr4[i+2], x3 = xr4[i+3];
        float4 c0 = cr[i+0],  c1 = cr[i+1],  c2 = cr[i+2],  c3 = cr[i+3];
        a0 += x0.x*c0.x + x0.y*c0.y + x0.z*c0.z + x0.w*c0.w;
        a1 += x1.x*c1.x + x1.y*c1.y + x1.z*c1.z + x1.w*c1.w;
        a2 += x2.x*c2.x + x2.y*c2.y + x2.z*c2.z + x2.w*c2.w;
        a3 += x3.x*c3.x + x3.y*c3.y + x3.z*c3.z + x3.w*c3.w;
    }
    return (a0 + a1) + (a2 + a3);
}

// ------------- stage 1: grid 2048 = 256 token-blocks x 8 splits -------------
// split = blockIdx&7 (XCD-affine -> 1.05 MB hi+lo slice per XCD L2).
// Block: 64 tokens x 2048-code slice, 8 waves. Every wave covers ALL 64 tokens
// (tt=4 tiles); wave w streams code tiles (j*8 + w)*16, j=0..15.
__global__ __launch_bounds__(512, 2) void lfq_stage1(
    const float* __restrict__ xf,
    const unsigned short* __restrict__ ch, const unsigned short* __restrict__ cl,
    float* __restrict__ sb1, float* __restrict__ sb2,
    int* __restrict__ si1, int* __restrict__ si2)
{
    const int split = blockIdx.x & 7;
    const int tb    = blockIdx.x >> 3;
    const int t0    = tb * 64;
    const int tid   = threadIdx.x;
    const int q     = tid >> 6;       // wave id = code-stream id, 0..7
    const int lane  = tid & 63;
    const int n     = lane & 15;
    const int quad  = lane >> 4;

    // A fragments: fp32 x -> bf16 hi/lo in registers. 4 token-tiles x 4 kk.
    bf16x8 ah[4][4], al[4][4];
#pragma unroll
    for (int tt = 0; tt < 4; ++tt) {
        const float* xr = xf + (size_t)(t0 + tt * 16 + n) * ND + quad * 8;
#pragma unroll
        for (int kk = 0; kk < 4; ++kk) {
            float4 v0 = *(const float4*)(xr + kk * 32);
            float4 v1 = *(const float4*)(xr + kk * 32 + 4);
            u16x8 hu, lu;
            hu[0] = f2bf(v0.x); lu[0] = f2bf(v0.x - bf2f(hu[0]));
            hu[1] = f2bf(v0.y); lu[1] = f2bf(v0.y - bf2f(hu[1]));
            hu[2] = f2bf(v0.z); lu[2] = f2bf(v0.z - bf2f(hu[2]));
            hu[3] = f2bf(v0.w); lu[3] = f2bf(v0.w - bf2f(hu[3]));
            hu[4] = f2bf(v1.x); lu[4] = f2bf(v1.x - bf2f(hu[4]));
            hu[5] = f2bf(v1.y); lu[5] = f2bf(v1.y - bf2f(hu[5]));
            hu[6] = f2bf(v1.z); lu[6] = f2bf(v1.z - bf2f(hu[6]));
            hu[7] = f2bf(v1.w); lu[7] = f2bf(v1.w - bf2f(hu[7]));
            ah[tt][kk] = u2b(hu);
            al[tt][kk] = u2b(lu);
        }
    }

    // j-packed top-2 per accumulator slot (low 4 mantissa bits = 15-j)
    float b1[4][4], b2[4][4];
#pragma unroll
    for (int tt = 0; tt < 4; ++tt)
#pragma unroll
        for (int r = 0; r < 4; ++r) { b1[tt][r] = -3.0e38f; b2[tt][r] = -3.0e38f; }

    const int cb_base = split * (NC / NSPLIT);   // 2048-code slice
    const size_t bofs = (size_t)(cb_base + q * 16 + n) * ND + quad * 8;
    const unsigned short* pBh = ch + bofs;
    const unsigned short* pBl = cl + bofs;

    bf16x8 Bh[2][4], Bl[2][4];
#pragma unroll
    for (int kk = 0; kk < 4; ++kk) {
        Bh[0][kk] = *(const bf16x8*)(pBh + kk * 32);
        Bl[0][kk] = *(const bf16x8*)(pBl + kk * 32);
    }

#pragma unroll 2   // CRITICAL: cur/nxt must be compile-time (round-6 lesson)
    for (int j = 0; j < 16; ++j) {
        const int cur = j & 1, nxt = cur ^ 1;
        if (j < 15) {   // next tile is 128 codes ahead (8 waves x 16)
            const unsigned short* p1h = pBh + (size_t)(j + 1) * (128 * ND);
            const unsigned short* p1l = pBl + (size_t)(j + 1) * (128 * ND);
#pragma unroll
            for (int kk = 0; kk < 4; ++kk) {
                Bh[nxt][kk] = *(const bf16x8*)(p1h + kk * 32);
                Bl[nxt][kk] = *(const bf16x8*)(p1l + kk * 32);
            }
        }
        const unsigned pk = (unsigned)(15 - j);   // bigger pk = smaller code
#pragma unroll
        for (int tt = 0; tt < 4; ++tt) {
            f32x4 acc = {0.f, 0.f, 0.f, 0.f};
#pragma unroll
            for (int kk = 0; kk < 4; ++kk) {
                acc = __builtin_amdgcn_mfma_f32_16x16x32_bf16(ah[tt][kk], Bh[cur][kk], acc, 0, 0, 0);
                acc = __builtin_amdgcn_mfma_f32_16x16x32_bf16(ah[tt][kk], Bl[cur][kk], acc, 0, 0, 0);
                acc = __builtin_amdgcn_mfma_f32_16x16x32_bf16(al[tt][kk], Bh[cur][kk], acc, 0, 0, 0);
            }
#pragma unroll
            for (int r = 0; r < 4; ++r) {
                float p = __uint_as_float((__float_as_uint(acc[r]) & 0xFFFFFFF0u) | pk);
                b2[tt][r] = __builtin_amdgcn_fmed3f(p, b1[tt][r], b2[tt][r]); // new 2nd
                b1[tt][r] = fmaxf(p, b1[tt][r]);
            }
        }
    }

    // unpack (score, code) and cross-lane top-2 merge over 16 code-lanes
    float v1[4][4], v2[4][4];
    int   c1[4][4], c2[4][4];
#pragma unroll
    for (int tt = 0; tt < 4; ++tt)
#pragma unroll
        for (int r = 0; r < 4; ++r) {
            int j1 = 15 - (int)(__float_as_uint(b1[tt][r]) & 15u);
            int j2 = 15 - (int)(__float_as_uint(b2[tt][r]) & 15u);
            v1[tt][r] = b1[tt][r]; c1[tt][r] = cb_base + (j1 * 8 + q) * 16 + n;
            v2[tt][r] = b2[tt][r]; c2[tt][r] = cb_base + (j2 * 8 + q) * 16 + n;
        }

#pragma unroll
    for (int tt = 0; tt < 4; ++tt)
#pragma unroll
        for (int r = 0; r < 4; ++r) {
#pragma unroll
            for (int off = 1; off < 16; off <<= 1) {
                float ob1 = __shfl_xor(v1[tt][r], off, 64);
                int   oi1 = __shfl_xor(c1[tt][r], off, 64);
                float ob2 = __shfl_xor(v2[tt][r], off, 64);
                int   oi2 = __shfl_xor(c2[tt][r], off, 64);
                bool gt = (ob1 > v1[tt][r]) ||
                          (ob1 == v1[tt][r] && oi1 < c1[tt][r]);
                float ls = gt ? v1[tt][r] : ob1;    // loser of top-1 duel
                int   li = gt ? c1[tt][r] : oi1;
                float ws_ = gt ? ob2 : v2[tt][r];   // winner's runner-up
                int   wi = gt ? oi2 : c2[tt][r];
                bool s2 = (ls > ws_) || (ls == ws_ && li < wi);
                v2[tt][r] = s2 ? ls : ws_;
                c2[tt][r] = s2 ? li : wi;
                v1[tt][r] = gt ? ob1 : v1[tt][r];
                c1[tt][r] = gt ? oi1 : c1[tt][r];
            }
        }

    // per-wave top-2 -> LDS, then cross-wave merge (8 disjoint code streams)
    __shared__ float lb1[8][64], lb2[8][64];
    __shared__ int   li1[8][64], li2[8][64];
    if (n == 0) {
#pragma unroll
        for (int tt = 0; tt < 4; ++tt)
#pragma unroll
            for (int r = 0; r < 4; ++r) {
                const int tk = tt * 16 + quad * 4 + r;
                lb1[q][tk] = v1[tt][r]; li1[q][tk] = c1[tt][r];
                lb2[q][tk] = v2[tt][r]; li2[q][tk] = c2[tt][r];
            }
    }
    __syncthreads();

    if (tid < 64) {
        float B1 = lb1[0][tid], B2 = lb2[0][tid];
        int   I1 = li1[0][tid], I2 = li2[0][tid];
#pragma unroll
        for (int qq = 1; qq < 8; ++qq) {
            float ob1 = lb1[qq][tid], ob2 = lb2[qq][tid];
            int   oi1 = li1[qq][tid], oi2 = li2[qq][tid];
            bool gt = (ob1 > B1) || (ob1 == B1 && oi1 < I1);
            float ls = gt ? B1 : ob1;  int li = gt ? I1 : oi1;
            float ws_ = gt ? ob2 : B2; int wi = gt ? I2 : oi2;
            bool s2 = (ls > ws_) || (ls == ws_ && li < wi);
            B2 = s2 ? ls : ws_;  I2 = s2 ? li : wi;
            B1 = gt ? ob1 : B1;  I1 = gt ? oi1 : I1;
        }
        const size_t o = (size_t)split * NT + t0 + tid;
        sb1[o] = B1; si1[o] = I1;
        sb2[o] = B2; si2[o] = I2;
    }
}

// ------------- combine: merge 8 splits, exact-rescore margin band -------------
__global__ __launch_bounds__(256) void lfq_combine(
    const float* __restrict__ sb1, const float* __restrict__ sb2,
    const int* __restrict__ si1, const int* __restrict__ si2,
    const float* __restrict__ xf, const float* __restrict__ cf,
    float* __restrict__ out, int out_size)
{
    const int t = blockIdx.x * 256 + threadIdx.x;   // 64 blocks -> 16384

    float v[16]; int id[16];
#pragma unroll
    for (int s = 0; s < NSPLIT; ++s) {
        const size_t o = (size_t)s * NT + t;
        v[2*s]   = sb1[o]; id[2*s]   = si1[o];
        v[2*s+1] = sb2[o]; id[2*s+1] = si2[o];
    }
    float A1 = v[0]; int I1 = id[0];
#pragma unroll
    for (int k = 1; k < 16; ++k)
        if (v[k] > A1 || (v[k] == A1 && id[k] < I1)) { A1 = v[k]; I1 = id[k]; }

    float4 xr4[32];
    const float4* xrow = (const float4*)(xf + (size_t)t * ND);
#pragma unroll
    for (int i = 0; i < 32; ++i) xr4[i] = xrow[i];

    float bs = -__builtin_inff(); int bi = 0; bool have = false;
#pragma unroll
    for (int k = 0; k < 16; ++k) {
        if (v[k] >= A1 - MARGIN) {
            float s = exact_dot(xr4, cf, id[k]);
            if (!have || s > bs || (s == bs && id[k] < bi)) { bs = s; bi = id[k]; have = true; }
        }
    }
    out[t] = (float)bi;
    if (t == 0 && out_size > NT) out[NT] = 0.0f;
}

// ------------- fallback: round-3 exact fp32 kernel (tiny ws) -------------
__global__ __launch_bounds__(512) void lfq_fp32_argmax(
    const float* __restrict__ xf, const float* __restrict__ cf,
    float* __restrict__ out, int out_size)
{
    const int tid = threadIdx.x;
    const int w   = tid >> 6;
    const int tok = tid & 63;
    const int t0  = blockIdx.x * 64;
    __shared__ float s_sc[8][64];
    __shared__ int   s_ix[8][64];

    float4 xr[32];
    const float4* xrow = (const float4*)(xf + (size_t)(t0 + tok) * ND);
#pragma unroll
    for (int i = 0; i < 32; ++i) xr[i] = xrow[i];

    float bs = -__builtin_inff();
    int   bi = 0;
    const int c_begin = w * (NC / 8);
    for (int c = c_begin; c < c_begin + NC / 8; ++c) {
        float s = exact_dot(xr, cf, c);
        if (s > bs) { bs = s; bi = c; }
    }
    s_sc[w][tok] = bs; s_ix[w][tok] = bi;
    __syncthreads();
    if (tid < 64) {
        float bsf = s_sc[0][tid]; int bif = s_ix[0][tid];
#pragma unroll
        for (int ww = 1; ww < 8; ++ww) {
            float s2 = s_sc[ww][tid]; int ii = s_ix[ww][tid];
            if (s2 > bsf || (s2 == bsf && ii < bif)) { bsf = s2; bif = ii; }
        }
        out[t0 + tid] = (float)bif;
    }
    if (blockIdx.x == 0 && tid == 0 && out_size > NT) out[NT] = 0.0f;
}

extern "C" void kernel_launch(void* const* d_in, const int* in_sizes, int n_in,
                              void* d_out, int out_size, void* d_ws, size_t ws_size,
                              hipStream_t stream) {
    const float* x  = (const float*)d_in[0];
    const float* cb = (const float*)d_in[1];
    float* out = (float*)d_out;

    // ws: ch 4.19MB | cl 4.19MB | sb1/sb2/si1/si2 512KB each  -> ~10.5 MB
    const size_t NCE = (size_t)NC * ND;          // 2,097,152 codebook elements
    const size_t NEED = NCE * 2 * 2 + (size_t)NT * NSPLIT * 4 * 4;
    if (ws_size >= NEED) {
        char* ws = (char*)d_ws;
        unsigned short* ch = (unsigned short*)ws;
        unsigned short* cl = (unsigned short*)(ws + NCE * 2);
        char* sp = ws + NCE * 4;
        float* sb1 = (float*)sp;
        float* sb2 = (float*)(sp + (size_t)NT * NSPLIT * 4);
        int*   si1 = (int*)  (sp + (size_t)NT * NSPLIT * 8);
        int*   si2 = (int*)  (sp + (size_t)NT * NSPLIT * 12);

        lfq_convert_cb<<<dim3(1024), dim3(512), 0, stream>>>(
            (const float4*)cb, (ushort4*)ch, (ushort4*)cl);
        lfq_stage1<<<dim3(256 * NSPLIT), dim3(512), 0, stream>>>(
            x, ch, cl, sb1, sb2, si1, si2);
        lfq_combine<<<dim3(64), dim3(256), 0, stream>>>(
            sb1, sb2, si1, si2, x, cb, out, out_size);
    } else {
        lfq_fp32_argmax<<<dim3(NT / 64), dim3(512), 0, stream>>>(x, cb, out, out_size);
    }
}

// Round 9
// 521.615 us; speedup vs baseline: 20.2391x; 1.0015x over previous
//
#include <hip/hip_runtime.h>
#include <hip/hip_bf16.h>

// LFQ argmax, round 9: round-8 structure, spill fixed.
//  ROOT CAUSE of r8's 232 MB WRITE_SIZE: __launch_bounds__(512,2) capped
//  VGPRs at 128 while tt=4 needs ~240 (A hi/lo 128 + B dbuf 64 + state 32).
//  -> __launch_bounds__(512,1): 256-VGPR budget (8-wave block still forces
//  2 waves/SIMD residency; occupancy unchanged at ~25%).
// Design (validated r8, modulo spill): block = 64 tokens x 2048-code
// XCD-affine slice; every wave covers all 64 tokens (tt=4), waves split codes
// 8-way (q=w) -> each B byte read once per block, 48 MFMAs per 8-load batch.
// Numerics (validated r6-r8): 3-term split-bf16, j-packed top-2 (4 low
// mantissa bits = 15-j), per-split top-2, exact rescore of MARGIN band.
// Output float32[16385].
#define NT 16384
#define ND 128
#define NC 16384
#define NSPLIT 8
#define MARGIN 0.02f   // >100x the (split + packing) comparison error

typedef __bf16 bf16x8 __attribute__((ext_vector_type(8)));
typedef unsigned short u16x8 __attribute__((ext_vector_type(8)));
typedef float f32x4 __attribute__((ext_vector_type(4)));

// RNE fp32->bf16 as pure bit ops (no address-taking; data finite)
static __device__ __forceinline__ unsigned short f2bf(float f) {
    unsigned u = __float_as_uint(f);
    return (unsigned short)((u + 0x7FFFu + ((u >> 16) & 1u)) >> 16);
}
static __device__ __forceinline__ float bf2f(unsigned short u) {
    return __uint_as_float(((unsigned)u) << 16);
}
static __device__ __forceinline__ bf16x8 u2b(u16x8 u) {
    return __builtin_bit_cast(bf16x8, u);
}

// ---------------- codebook fp32 -> bf16 hi/lo split ----------------
__global__ __launch_bounds__(512) void lfq_convert_cb(
    const float4* __restrict__ cb4, ushort4* __restrict__ ch, ushort4* __restrict__ cl)
{
    const unsigned i = blockIdx.x * 512 + threadIdx.x;   // 0..524287
    float4 v = cb4[i];
    ushort4 h, l;
    h.x = f2bf(v.x); l.x = f2bf(v.x - bf2f(h.x));
    h.y = f2bf(v.y); l.y = f2bf(v.y - bf2f(h.y));
    h.z = f2bf(v.z); l.z = f2bf(v.z - bf2f(h.z));
    h.w = f2bf(v.w); l.w = f2bf(v.w - bf2f(h.w));
    ch[i] = h; cl[i] = l;
}

// round-3/4-validated exact fp32 dot
static __device__ __forceinline__ float exact_dot(
    const float4* __restrict__ xr4, const float* __restrict__ cf, int cidx)
{
    const float4* cr = (const float4*)(cf + (size_t)cidx * ND);
    float a0 = 0.f, a1 = 0.f, a2 = 0.f, a3 = 0.f;
#pragma unroll
    for (int i = 0; i < 32; i += 4) {
        float4 x0 = xr4[i+0], x1 = xr4[i+1], x2 = xr4[i+2], x3 = xr4[i+3];
        float4 c0 = cr[i+0],  c1 = cr[i+1],  c2 = cr[i+2],  c3 = cr[i+3];
        a0 += x0.x*c0.x + x0.y*c0.y + x0.z*c0.z + x0.w*c0.w;
        a1 += x1.x*c1.x + x1.y*c1.y + x1.z*c1.z + x1.w*c1.w;
        a2 += x2.x*c2.x + x2.y*c2.y + x2.z*c2.z + x2.w*c2.w;
        a3 += x3.x*c3.x + x3.y*c3.y + x3.z*c3.z + x3.w*c3.w;
    }
    return (a0 + a1) + (a2 + a3);
}

// ------------- stage 1: grid 2048 = 256 token-blocks x 8 splits -------------
// split = blockIdx&7 (XCD-affine -> 1.05 MB hi+lo slice per XCD L2).
__global__ __launch_bounds__(512, 1) void lfq_stage1(
    const float* __restrict__ xf,
    const unsigned short* __restrict__ ch, const unsigned short* __restrict__ cl,
    float* __restrict__ sb1, float* __restrict__ sb2,
    int* __restrict__ si1, int* __restrict__ si2)
{
    const int split = blockIdx.x & 7;
    const int tb    = blockIdx.x >> 3;
    const int t0    = tb * 64;
    const int tid   = threadIdx.x;
    const int q     = tid >> 6;       // wave id = code-stream id, 0..7
    const int lane  = tid & 63;
    const int n     = lane & 15;
    const int quad  = lane >> 4;

    // A fragments: fp32 x -> bf16 hi/lo in registers. 4 token-tiles x 4 kk.
    bf16x8 ah[4][4], al[4][4];
#pragma unroll
    for (int tt = 0; tt < 4; ++tt) {
        const float* xr = xf + (size_t)(t0 + tt * 16 + n) * ND + quad * 8;
#pragma unroll
        for (int kk = 0; kk < 4; ++kk) {
            float4 v0 = *(const float4*)(xr + kk * 32);
            float4 v1 = *(const float4*)(xr + kk * 32 + 4);
            u16x8 hu, lu;
            hu[0] = f2bf(v0.x); lu[0] = f2bf(v0.x - bf2f(hu[0]));
            hu[1] = f2bf(v0.y); lu[1] = f2bf(v0.y - bf2f(hu[1]));
            hu[2] = f2bf(v0.z); lu[2] = f2bf(v0.z - bf2f(hu[2]));
            hu[3] = f2bf(v0.w); lu[3] = f2bf(v0.w - bf2f(hu[3]));
            hu[4] = f2bf(v1.x); lu[4] = f2bf(v1.x - bf2f(hu[4]));
            hu[5] = f2bf(v1.y); lu[5] = f2bf(v1.y - bf2f(hu[5]));
            hu[6] = f2bf(v1.z); lu[6] = f2bf(v1.z - bf2f(hu[6]));
            hu[7] = f2bf(v1.w); lu[7] = f2bf(v1.w - bf2f(hu[7]));
            ah[tt][kk] = u2b(hu);
            al[tt][kk] = u2b(lu);
        }
    }

    // j-packed top-2 per accumulator slot (low 4 mantissa bits = 15-j)
    float b1[4][4], b2[4][4];
#pragma unroll
    for (int tt = 0; tt < 4; ++tt)
#pragma unroll
        for (int r = 0; r < 4; ++r) { b1[tt][r] = -3.0e38f; b2[tt][r] = -3.0e38f; }

    const int cb_base = split * (NC / NSPLIT);   // 2048-code slice
    const size_t bofs = (size_t)(cb_base + q * 16 + n) * ND + quad * 8;
    const unsigned short* pBh = ch + bofs;
    const unsigned short* pBl = cl + bofs;

    bf16x8 Bh[2][4], Bl[2][4];
#pragma unroll
    for (int kk = 0; kk < 4; ++kk) {
        Bh[0][kk] = *(const bf16x8*)(pBh + kk * 32);
        Bl[0][kk] = *(const bf16x8*)(pBl + kk * 32);
    }

#pragma unroll 2   // CRITICAL: cur/nxt must be compile-time (round-6 lesson)
    for (int j = 0; j < 16; ++j) {
        const int cur = j & 1, nxt = cur ^ 1;
        if (j < 15) {   // next tile is 128 codes ahead (8 waves x 16)
            const unsigned short* p1h = pBh + (size_t)(j + 1) * (128 * ND);
            const unsigned short* p1l = pBl + (size_t)(j + 1) * (128 * ND);
#pragma unroll
            for (int kk = 0; kk < 4; ++kk) {
                Bh[nxt][kk] = *(const bf16x8*)(p1h + kk * 32);
                Bl[nxt][kk] = *(const bf16x8*)(p1l + kk * 32);
            }
        }
        const unsigned pk = (unsigned)(15 - j);   // bigger pk = smaller code
#pragma unroll
        for (int tt = 0; tt < 4; ++tt) {
            f32x4 acc = {0.f, 0.f, 0.f, 0.f};
#pragma unroll
            for (int kk = 0; kk < 4; ++kk) {
                acc = __builtin_amdgcn_mfma_f32_16x16x32_bf16(ah[tt][kk], Bh[cur][kk], acc, 0, 0, 0);
                acc = __builtin_amdgcn_mfma_f32_16x16x32_bf16(ah[tt][kk], Bl[cur][kk], acc, 0, 0, 0);
                acc = __builtin_amdgcn_mfma_f32_16x16x32_bf16(al[tt][kk], Bh[cur][kk], acc, 0, 0, 0);
            }
#pragma unroll
            for (int r = 0; r < 4; ++r) {
                float p = __uint_as_float((__float_as_uint(acc[r]) & 0xFFFFFFF0u) | pk);
                b2[tt][r] = __builtin_amdgcn_fmed3f(p, b1[tt][r], b2[tt][r]); // new 2nd
                b1[tt][r] = fmaxf(p, b1[tt][r]);
            }
        }
    }

    // unpack (score, code) and cross-lane top-2 merge over 16 code-lanes
    float v1[4][4], v2[4][4];
    int   c1[4][4], c2[4][4];
#pragma unroll
    for (int tt = 0; tt < 4; ++tt)
#pragma unroll
        for (int r = 0; r < 4; ++r) {
            int j1 = 15 - (int)(__float_as_uint(b1[tt][r]) & 15u);
            int j2 = 15 - (int)(__float_as_uint(b2[tt][r]) & 15u);
            v1[tt][r] = b1[tt][r]; c1[tt][r] = cb_base + (j1 * 8 + q) * 16 + n;
            v2[tt][r] = b2[tt][r]; c2[tt][r] = cb_base + (j2 * 8 + q) * 16 + n;
        }

#pragma unroll
    for (int tt = 0; tt < 4; ++tt)
#pragma unroll
        for (int r = 0; r < 4; ++r) {
#pragma unroll
            for (int off = 1; off < 16; off <<= 1) {
                float ob1 = __shfl_xor(v1[tt][r], off, 64);
                int   oi1 = __shfl_xor(c1[tt][r], off, 64);
                float ob2 = __shfl_xor(v2[tt][r], off, 64);
                int   oi2 = __shfl_xor(c2[tt][r], off, 64);
                bool gt = (ob1 > v1[tt][r]) ||
                          (ob1 == v1[tt][r] && oi1 < c1[tt][r]);
                float ls = gt ? v1[tt][r] : ob1;    // loser of top-1 duel
                int   li = gt ? c1[tt][r] : oi1;
                float ws_ = gt ? ob2 : v2[tt][r];   // winner's runner-up
                int   wi = gt ? oi2 : c2[tt][r];
                bool s2 = (ls > ws_) || (ls == ws_ && li < wi);
                v2[tt][r] = s2 ? ls : ws_;
                c2[tt][r] = s2 ? li : wi;
                v1[tt][r] = gt ? ob1 : v1[tt][r];
                c1[tt][r] = gt ? oi1 : c1[tt][r];
            }
        }

    // per-wave top-2 -> LDS, then cross-wave merge (8 disjoint code streams)
    __shared__ float lb1[8][64], lb2[8][64];
    __shared__ int   li1[8][64], li2[8][64];
    if (n == 0) {
#pragma unroll
        for (int tt = 0; tt < 4; ++tt)
#pragma unroll
            for (int r = 0; r < 4; ++r) {
                const int tk = tt * 16 + quad * 4 + r;
                lb1[q][tk] = v1[tt][r]; li1[q][tk] = c1[tt][r];
                lb2[q][tk] = v2[tt][r]; li2[q][tk] = c2[tt][r];
            }
    }
    __syncthreads();

    if (tid < 64) {
        float B1 = lb1[0][tid], B2 = lb2[0][tid];
        int   I1 = li1[0][tid], I2 = li2[0][tid];
#pragma unroll
        for (int qq = 1; qq < 8; ++qq) {
            float ob1 = lb1[qq][tid], ob2 = lb2[qq][tid];
            int   oi1 = li1[qq][tid], oi2 = li2[qq][tid];
            bool gt = (ob1 > B1) || (ob1 == B1 && oi1 < I1);
            float ls = gt ? B1 : ob1;  int li = gt ? I1 : oi1;
            float ws_ = gt ? ob2 : B2; int wi = gt ? I2 : oi2;
            bool s2 = (ls > ws_) || (ls == ws_ && li < wi);
            B2 = s2 ? ls : ws_;  I2 = s2 ? li : wi;
            B1 = gt ? ob1 : B1;  I1 = gt ? oi1 : I1;
        }
        const size_t o = (size_t)split * NT + t0 + tid;
        sb1[o] = B1; si1[o] = I1;
        sb2[o] = B2; si2[o] = I2;
    }
}

// ------------- combine: merge 8 splits, exact-rescore margin band -------------
__global__ __launch_bounds__(256) void lfq_combine(
    const float* __restrict__ sb1, const float* __restrict__ sb2,
    const int* __restrict__ si1, const int* __restrict__ si2,
    const float* __restrict__ xf, const float* __restrict__ cf,
    float* __restrict__ out, int out_size)
{
    const int t = blockIdx.x * 256 + threadIdx.x;   // 64 blocks -> 16384

    float v[16]; int id[16];
#pragma unroll
    for (int s = 0; s < NSPLIT; ++s) {
        const size_t o = (size_t)s * NT + t;
        v[2*s]   = sb1[o]; id[2*s]   = si1[o];
        v[2*s+1] = sb2[o]; id[2*s+1] = si2[o];
    }
    float A1 = v[0]; int I1 = id[0];
#pragma unroll
    for (int k = 1; k < 16; ++k)
        if (v[k] > A1 || (v[k] == A1 && id[k] < I1)) { A1 = v[k]; I1 = id[k]; }

    float4 xr4[32];
    const float4* xrow = (const float4*)(xf + (size_t)t * ND);
#pragma unroll
    for (int i = 0; i < 32; ++i) xr4[i] = xrow[i];

    float bs = -__builtin_inff(); int bi = 0; bool have = false;
#pragma unroll
    for (int k = 0; k < 16; ++k) {
        if (v[k] >= A1 - MARGIN) {
            float s = exact_dot(xr4, cf, id[k]);
            if (!have || s > bs || (s == bs && id[k] < bi)) { bs = s; bi = id[k]; have = true; }
        }
    }
    out[t] = (float)bi;
    if (t == 0 && out_size > NT) out[NT] = 0.0f;
}

// ------------- fallback: round-3 exact fp32 kernel (tiny ws) -------------
__global__ __launch_bounds__(512) void lfq_fp32_argmax(
    const float* __restrict__ xf, const float* __restrict__ cf,
    float* __restrict__ out, int out_size)
{
    const int tid = threadIdx.x;
    const int w   = tid >> 6;
    const int tok = tid & 63;
    const int t0  = blockIdx.x * 64;
    __shared__ float s_sc[8][64];
    __shared__ int   s_ix[8][64];

    float4 xr[32];
    const float4* xrow = (const float4*)(xf + (size_t)(t0 + tok) * ND);
#pragma unroll
    for (int i = 0; i < 32; ++i) xr[i] = xrow[i];

    float bs = -__builtin_inff();
    int   bi = 0;
    const int c_begin = w * (NC / 8);
    for (int c = c_begin; c < c_begin + NC / 8; ++c) {
        float s = exact_dot(xr, cf, c);
        if (s > bs) { bs = s; bi = c; }
    }
    s_sc[w][tok] = bs; s_ix[w][tok] = bi;
    __syncthreads();
    if (tid < 64) {
        float bsf = s_sc[0][tid]; int bif = s_ix[0][tid];
#pragma unroll
        for (int ww = 1; ww < 8; ++ww) {
            float s2 = s_sc[ww][tid]; int ii = s_ix[ww][tid];
            if (s2 > bsf || (s2 == bsf && ii < bif)) { bsf = s2; bif = ii; }
        }
        out[t0 + tid] = (float)bif;
    }
    if (blockIdx.x == 0 && tid == 0 && out_size > NT) out[NT] = 0.0f;
}

extern "C" void kernel_launch(void* const* d_in, const int* in_sizes, int n_in,
                              void* d_out, int out_size, void* d_ws, size_t ws_size,
                              hipStream_t stream) {
    const float* x  = (const float*)d_in[0];
    const float* cb = (const float*)d_in[1];
    float* out = (float*)d_out;

    // ws: ch 4.19MB | cl 4.19MB | sb1/sb2/si1/si2 512KB each  -> ~10.5 MB
    const size_t NCE = (size_t)NC * ND;          // 2,097,152 codebook elements
    const size_t NEED = NCE * 2 * 2 + (size_t)NT * NSPLIT * 4 * 4;
    if (ws_size >= NEED) {
        char* ws = (char*)d_ws;
        unsigned short* ch = (unsigned short*)ws;
        unsigned short* cl = (unsigned short*)(ws + NCE * 2);
        char* sp = ws + NCE * 4;
        float* sb1 = (float*)sp;
        float* sb2 = (float*)(sp + (size_t)NT * NSPLIT * 4);
        int*   si1 = (int*)  (sp + (size_t)NT * NSPLIT * 8);
        int*   si2 = (int*)  (sp + (size_t)NT * NSPLIT * 12);

        lfq_convert_cb<<<dim3(1024), dim3(512), 0, stream>>>(
            (const float4*)cb, (ushort4*)ch, (ushort4*)cl);
        lfq_stage1<<<dim3(256 * NSPLIT), dim3(512), 0, stream>>>(
            x, ch, cl, sb1, sb2, si1, si2);
        lfq_combine<<<dim3(64), dim3(256), 0, stream>>>(
            sb1, sb2, si1, si2, x, cb, out, out_size);
    } else {
        lfq_fp32_argmax<<<dim3(NT / 64), dim3(512), 0, stream>>>(x, cb, out, out_size);
    }
}

// Round 10
// 428.928 us; speedup vs baseline: 24.6126x; 1.2161x over previous
//
#include <hip/hip_runtime.h>
#include <hip/hip_bf16.h>

// LFQ argmax, round 10: r8/r9 structure, spill REALLY fixed.
//  ROOT CAUSE chain: tt=4 needs ~240 VGPRs. An 8-wave (512-thr) block forces
//  >=2 waves/SIMD, and the backend's occupancy heuristic allocated for 4
//  waves/EU = 128 VGPRs -> 232 MB scratch spill (identical r8 & r9 counters;
//  launch_bounds(512,1) is unexpressible for an 8-wave block).
//  FIX: 4-wave block (256 thr) + __launch_bounds__(256,1) -> 1 wave/SIMD
//  feasible, register budget up to 512, no spill.
// Design: block = 64 tokens x 2048-code XCD-affine slice; every wave covers
// all 64 tokens (tt=4 -> each B byte feeds 48 MFMAs), 4 waves split the code
// tiles (q=tid>>6, tiles j*4+q, j=0..31 — r7's proven mapping & 5-bit pack).
// Numerics (validated r6-r9): 3-term split-bf16, j-packed top-2, per-split
// top-2, exact rescore of MARGIN band. Output float32[16385].
#define NT 16384
#define ND 128
#define NC 16384
#define NSPLIT 8
#define MARGIN 0.02f   // >100x the (split + packing) comparison error

typedef __bf16 bf16x8 __attribute__((ext_vector_type(8)));
typedef unsigned short u16x8 __attribute__((ext_vector_type(8)));
typedef float f32x4 __attribute__((ext_vector_type(4)));

// RNE fp32->bf16 as pure bit ops (no address-taking; data finite)
static __device__ __forceinline__ unsigned short f2bf(float f) {
    unsigned u = __float_as_uint(f);
    return (unsigned short)((u + 0x7FFFu + ((u >> 16) & 1u)) >> 16);
}
static __device__ __forceinline__ float bf2f(unsigned short u) {
    return __uint_as_float(((unsigned)u) << 16);
}
static __device__ __forceinline__ bf16x8 u2b(u16x8 u) {
    return __builtin_bit_cast(bf16x8, u);
}

// ---------------- codebook fp32 -> bf16 hi/lo split ----------------
__global__ __launch_bounds__(512) void lfq_convert_cb(
    const float4* __restrict__ cb4, ushort4* __restrict__ ch, ushort4* __restrict__ cl)
{
    const unsigned i = blockIdx.x * 512 + threadIdx.x;   // 0..524287
    float4 v = cb4[i];
    ushort4 h, l;
    h.x = f2bf(v.x); l.x = f2bf(v.x - bf2f(h.x));
    h.y = f2bf(v.y); l.y = f2bf(v.y - bf2f(h.y));
    h.z = f2bf(v.z); l.z = f2bf(v.z - bf2f(h.z));
    h.w = f2bf(v.w); l.w = f2bf(v.w - bf2f(h.w));
    ch[i] = h; cl[i] = l;
}

// round-3/4-validated exact fp32 dot
static __device__ __forceinline__ float exact_dot(
    const float4* __restrict__ xr4, const float* __restrict__ cf, int cidx)
{
    const float4* cr = (const float4*)(cf + (size_t)cidx * ND);
    float a0 = 0.f, a1 = 0.f, a2 = 0.f, a3 = 0.f;
#pragma unroll
    for (int i = 0; i < 32; i += 4) {
        float4 x0 = xr4[i+0], x1 = xr4[i+1], x2 = xr4[i+2], x3 = xr4[i+3];
        float4 c0 = cr[i+0],  c1 = cr[i+1],  c2 = cr[i+2],  c3 = cr[i+3];
        a0 += x0.x*c0.x + x0.y*c0.y + x0.z*c0.z + x0.w*c0.w;
        a1 += x1.x*c1.x + x1.y*c1.y + x1.z*c1.z + x1.w*c1.w;
        a2 += x2.x*c2.x + x2.y*c2.y + x2.z*c2.z + x2.w*c2.w;
        a3 += x3.x*c3.x + x3.y*c3.y + x3.z*c3.z + x3.w*c3.w;
    }
    return (a0 + a1) + (a2 + a3);
}

// ------------- stage 1: grid 2048 = 256 token-blocks x 8 splits -------------
// split = blockIdx&7 (XCD-affine -> 1.05 MB hi+lo slice per XCD L2).
// Block: 256 threads = 4 waves; each wave covers all 64 tokens (tt=4) and
// streams code tiles (j*4 + q)*16, j=0..31, stride 64 codes.
__global__ __launch_bounds__(256, 1) void lfq_stage1(
    const float* __restrict__ xf,
    const unsigned short* __restrict__ ch, const unsigned short* __restrict__ cl,
    float* __restrict__ sb1, float* __restrict__ sb2,
    int* __restrict__ si1, int* __restrict__ si2)
{
    const int split = blockIdx.x & 7;
    const int tb    = blockIdx.x >> 3;
    const int t0    = tb * 64;
    const int tid   = threadIdx.x;
    const int q     = tid >> 6;       // wave id = code-stream id, 0..3
    const int lane  = tid & 63;
    const int n     = lane & 15;
    const int quad  = lane >> 4;

    // A fragments: fp32 x -> bf16 hi/lo in registers. 4 token-tiles x 4 kk.
    bf16x8 ah[4][4], al[4][4];
#pragma unroll
    for (int tt = 0; tt < 4; ++tt) {
        const float* xr = xf + (size_t)(t0 + tt * 16 + n) * ND + quad * 8;
#pragma unroll
        for (int kk = 0; kk < 4; ++kk) {
            float4 v0 = *(const float4*)(xr + kk * 32);
            float4 v1 = *(const float4*)(xr + kk * 32 + 4);
            u16x8 hu, lu;
            hu[0] = f2bf(v0.x); lu[0] = f2bf(v0.x - bf2f(hu[0]));
            hu[1] = f2bf(v0.y); lu[1] = f2bf(v0.y - bf2f(hu[1]));
            hu[2] = f2bf(v0.z); lu[2] = f2bf(v0.z - bf2f(hu[2]));
            hu[3] = f2bf(v0.w); lu[3] = f2bf(v0.w - bf2f(hu[3]));
            hu[4] = f2bf(v1.x); lu[4] = f2bf(v1.x - bf2f(hu[4]));
            hu[5] = f2bf(v1.y); lu[5] = f2bf(v1.y - bf2f(hu[5]));
            hu[6] = f2bf(v1.z); lu[6] = f2bf(v1.z - bf2f(hu[6]));
            hu[7] = f2bf(v1.w); lu[7] = f2bf(v1.w - bf2f(hu[7]));
            ah[tt][kk] = u2b(hu);
            al[tt][kk] = u2b(lu);
        }
    }

    // j-packed top-2 per accumulator slot (low 5 mantissa bits = 31-j)
    float b1[4][4], b2[4][4];
#pragma unroll
    for (int tt = 0; tt < 4; ++tt)
#pragma unroll
        for (int r = 0; r < 4; ++r) { b1[tt][r] = -3.0e38f; b2[tt][r] = -3.0e38f; }

    const int cb_base = split * (NC / NSPLIT);   // 2048-code slice
    const size_t bofs = (size_t)(cb_base + q * 16 + n) * ND + quad * 8;
    const unsigned short* pBh = ch + bofs;
    const unsigned short* pBl = cl + bofs;

    bf16x8 Bh[2][4], Bl[2][4];
#pragma unroll
    for (int kk = 0; kk < 4; ++kk) {
        Bh[0][kk] = *(const bf16x8*)(pBh + kk * 32);
        Bl[0][kk] = *(const bf16x8*)(pBl + kk * 32);
    }

#pragma unroll 2   // CRITICAL: cur/nxt must be compile-time (round-6 lesson)
    for (int j = 0; j < 32; ++j) {
        const int cur = j & 1, nxt = cur ^ 1;
        if (j < 31) {   // next tile is 64 codes ahead (4 waves x 16)
            const unsigned short* p1h = pBh + (size_t)(j + 1) * (64 * ND);
            const unsigned short* p1l = pBl + (size_t)(j + 1) * (64 * ND);
#pragma unroll
            for (int kk = 0; kk < 4; ++kk) {
                Bh[nxt][kk] = *(const bf16x8*)(p1h + kk * 32);
                Bl[nxt][kk] = *(const bf16x8*)(p1l + kk * 32);
            }
        }
        const unsigned pk = (unsigned)(31 - j);   // bigger pk = smaller code
#pragma unroll
        for (int tt = 0; tt < 4; ++tt) {
            f32x4 acc = {0.f, 0.f, 0.f, 0.f};
#pragma unroll
            for (int kk = 0; kk < 4; ++kk) {
                acc = __builtin_amdgcn_mfma_f32_16x16x32_bf16(ah[tt][kk], Bh[cur][kk], acc, 0, 0, 0);
                acc = __builtin_amdgcn_mfma_f32_16x16x32_bf16(ah[tt][kk], Bl[cur][kk], acc, 0, 0, 0);
                acc = __builtin_amdgcn_mfma_f32_16x16x32_bf16(al[tt][kk], Bh[cur][kk], acc, 0, 0, 0);
            }
#pragma unroll
            for (int r = 0; r < 4; ++r) {
                float p = __uint_as_float((__float_as_uint(acc[r]) & 0xFFFFFFE0u) | pk);
                b2[tt][r] = __builtin_amdgcn_fmed3f(p, b1[tt][r], b2[tt][r]); // new 2nd
                b1[tt][r] = fmaxf(p, b1[tt][r]);
            }
        }
    }

    // unpack (score, code) and cross-lane top-2 merge over 16 code-lanes
    float v1[4][4], v2[4][4];
    int   c1[4][4], c2[4][4];
#pragma unroll
    for (int tt = 0; tt < 4; ++tt)
#pragma unroll
        for (int r = 0; r < 4; ++r) {
            int j1 = 31 - (int)(__float_as_uint(b1[tt][r]) & 31u);
            int j2 = 31 - (int)(__float_as_uint(b2[tt][r]) & 31u);
            v1[tt][r] = b1[tt][r]; c1[tt][r] = cb_base + (j1 * 4 + q) * 16 + n;
            v2[tt][r] = b2[tt][r]; c2[tt][r] = cb_base + (j2 * 4 + q) * 16 + n;
        }

#pragma unroll
    for (int tt = 0; tt < 4; ++tt)
#pragma unroll
        for (int r = 0; r < 4; ++r) {
#pragma unroll
            for (int off = 1; off < 16; off <<= 1) {
                float ob1 = __shfl_xor(v1[tt][r], off, 64);
                int   oi1 = __shfl_xor(c1[tt][r], off, 64);
                float ob2 = __shfl_xor(v2[tt][r], off, 64);
                int   oi2 = __shfl_xor(c2[tt][r], off, 64);
                bool gt = (ob1 > v1[tt][r]) ||
                          (ob1 == v1[tt][r] && oi1 < c1[tt][r]);
                float ls = gt ? v1[tt][r] : ob1;    // loser of top-1 duel
                int   li = gt ? c1[tt][r] : oi1;
                float ws_ = gt ? ob2 : v2[tt][r];   // winner's runner-up
                int   wi = gt ? oi2 : c2[tt][r];
                bool s2 = (ls > ws_) || (ls == ws_ && li < wi);
                v2[tt][r] = s2 ? ls : ws_;
                c2[tt][r] = s2 ? li : wi;
                v1[tt][r] = gt ? ob1 : v1[tt][r];
                c1[tt][r] = gt ? oi1 : c1[tt][r];
            }
        }

    // per-wave top-2 -> LDS, then cross-wave merge (4 disjoint code streams)
    __shared__ float lb1[4][64], lb2[4][64];
    __shared__ int   li1[4][64], li2[4][64];
    if (n == 0) {
#pragma unroll
        for (int tt = 0; tt < 4; ++tt)
#pragma unroll
            for (int r = 0; r < 4; ++r) {
                const int tk = tt * 16 + quad * 4 + r;
                lb1[q][tk] = v1[tt][r]; li1[q][tk] = c1[tt][r];
                lb2[q][tk] = v2[tt][r]; li2[q][tk] = c2[tt][r];
            }
    }
    __syncthreads();

    if (tid < 64) {
        float B1 = lb1[0][tid], B2 = lb2[0][tid];
        int   I1 = li1[0][tid], I2 = li2[0][tid];
#pragma unroll
        for (int qq = 1; qq < 4; ++qq) {
            float ob1 = lb1[qq][tid], ob2 = lb2[qq][tid];
            int   oi1 = li1[qq][tid], oi2 = li2[qq][tid];
            bool gt = (ob1 > B1) || (ob1 == B1 && oi1 < I1);
            float ls = gt ? B1 : ob1;  int li = gt ? I1 : oi1;
            float ws_ = gt ? ob2 : B2; int wi = gt ? I2 : oi2;
            bool s2 = (ls > ws_) || (ls == ws_ && li < wi);
            B2 = s2 ? ls : ws_;  I2 = s2 ? li : wi;
            B1 = gt ? ob1 : B1;  I1 = gt ? oi1 : I1;
        }
        const size_t o = (size_t)split * NT + t0 + tid;
        sb1[o] = B1; si1[o] = I1;
        sb2[o] = B2; si2[o] = I2;
    }
}

// ------------- combine: merge 8 splits, exact-rescore margin band -------------
__global__ __launch_bounds__(256) void lfq_combine(
    const float* __restrict__ sb1, const float* __restrict__ sb2,
    const int* __restrict__ si1, const int* __restrict__ si2,
    const float* __restrict__ xf, const float* __restrict__ cf,
    float* __restrict__ out, int out_size)
{
    const int t = blockIdx.x * 256 + threadIdx.x;   // 64 blocks -> 16384

    float v[16]; int id[16];
#pragma unroll
    for (int s = 0; s < NSPLIT; ++s) {
        const size_t o = (size_t)s * NT + t;
        v[2*s]   = sb1[o]; id[2*s]   = si1[o];
        v[2*s+1] = sb2[o]; id[2*s+1] = si2[o];
    }
    float A1 = v[0]; int I1 = id[0];
#pragma unroll
    for (int k = 1; k < 16; ++k)
        if (v[k] > A1 || (v[k] == A1 && id[k] < I1)) { A1 = v[k]; I1 = id[k]; }

    float4 xr4[32];
    const float4* xrow = (const float4*)(xf + (size_t)t * ND);
#pragma unroll
    for (int i = 0; i < 32; ++i) xr4[i] = xrow[i];

    float bs = -__builtin_inff(); int bi = 0; bool have = false;
#pragma unroll
    for (int k = 0; k < 16; ++k) {
        if (v[k] >= A1 - MARGIN) {
            float s = exact_dot(xr4, cf, id[k]);
            if (!have || s > bs || (s == bs && id[k] < bi)) { bs = s; bi = id[k]; have = true; }
        }
    }
    out[t] = (float)bi;
    if (t == 0 && out_size > NT) out[NT] = 0.0f;
}

// ------------- fallback: round-3 exact fp32 kernel (tiny ws) -------------
__global__ __launch_bounds__(512) void lfq_fp32_argmax(
    const float* __restrict__ xf, const float* __restrict__ cf,
    float* __restrict__ out, int out_size)
{
    const int tid = threadIdx.x;
    const int w   = tid >> 6;
    const int tok = tid & 63;
    const int t0  = blockIdx.x * 64;
    __shared__ float s_sc[8][64];
    __shared__ int   s_ix[8][64];

    float4 xr[32];
    const float4* xrow = (const float4*)(xf + (size_t)(t0 + tok) * ND);
#pragma unroll
    for (int i = 0; i < 32; ++i) xr[i] = xrow[i];

    float bs = -__builtin_inff();
    int   bi = 0;
    const int c_begin = w * (NC / 8);
    for (int c = c_begin; c < c_begin + NC / 8; ++c) {
        float s = exact_dot(xr, cf, c);
        if (s > bs) { bs = s; bi = c; }
    }
    s_sc[w][tok] = bs; s_ix[w][tok] = bi;
    __syncthreads();
    if (tid < 64) {
        float bsf = s_sc[0][tid]; int bif = s_ix[0][tid];
#pragma unroll
        for (int ww = 1; ww < 8; ++ww) {
            float s2 = s_sc[ww][tid]; int ii = s_ix[ww][tid];
            if (s2 > bsf || (s2 == bsf && ii < bif)) { bsf = s2; bif = ii; }
        }
        out[t0 + tid] = (float)bif;
    }
    if (blockIdx.x == 0 && tid == 0 && out_size > NT) out[NT] = 0.0f;
}

extern "C" void kernel_launch(void* const* d_in, const int* in_sizes, int n_in,
                              void* d_out, int out_size, void* d_ws, size_t ws_size,
                              hipStream_t stream) {
    const float* x  = (const float*)d_in[0];
    const float* cb = (const float*)d_in[1];
    float* out = (float*)d_out;

    // ws: ch 4.19MB | cl 4.19MB | sb1/sb2/si1/si2 512KB each  -> ~10.5 MB
    const size_t NCE = (size_t)NC * ND;          // 2,097,152 codebook elements
    const size_t NEED = NCE * 2 * 2 + (size_t)NT * NSPLIT * 4 * 4;
    if (ws_size >= NEED) {
        char* ws = (char*)d_ws;
        unsigned short* ch = (unsigned short*)ws;
        unsigned short* cl = (unsigned short*)(ws + NCE * 2);
        char* sp = ws + NCE * 4;
        float* sb1 = (float*)sp;
        float* sb2 = (float*)(sp + (size_t)NT * NSPLIT * 4);
        int*   si1 = (int*)  (sp + (size_t)NT * NSPLIT * 8);
        int*   si2 = (int*)  (sp + (size_t)NT * NSPLIT * 12);

        lfq_convert_cb<<<dim3(1024), dim3(512), 0, stream>>>(
            (const float4*)cb, (ushort4*)ch, (ushort4*)cl);
        lfq_stage1<<<dim3(256 * NSPLIT), dim3(256), 0, stream>>>(
            x, ch, cl, sb1, sb2, si1, si2);
        lfq_combine<<<dim3(64), dim3(256), 0, stream>>>(
            sb1, sb2, si1, si2, x, cb, out, out_size);
    } else {
        lfq_fp32_argmax<<<dim3(NT / 64), dim3(512), 0, stream>>>(x, cb, out, out_size);
    }
}

// Round 11
// 257.778 us; speedup vs baseline: 40.9539x; 1.6639x over previous
//
#include <hip/hip_runtime.h>
#include <hip/hip_bf16.h>

// LFQ argmax, round 11: LDS-shared B stream (m97 pattern).
// r7/r10 forensics: B-bytes/dur = 7.8 / 5.4 TB/s -> the B stream is served by
// Infinity Cache at its ~7 TB/s ceiling; FETCH shows HBM sees it once. Fix =
// raise tokens-covered-per-B-read (T_cov). Registers cap T_cov at 64; LDS
// sharing lifts it to 256: block = 8 waves x 32 tokens (tt=2, A=64 VGPR/wave),
// all waves sweep the 2048-code slice from LDS (64-code hi+lo tiles, 32 KB,
// double-buffered 64 KB, global_load_lds width=16, 1 barrier/tile).
// L3 traffic 2.15 GB -> 537 MB. Convert writes tiles with per-row 16B-chunk
// rotation (pos=(chunk+row)&15) so ds_read_b128 is conflict-minimal.
// Numerics (validated r6-r10): 3-term split-bf16, j-packed top-2 (7 low
// mantissa bits = 127-jj), per-split top-2, exact rescore of MARGIN band.
// Output float32[16385].
#define NT 16384
#define ND 128
#define NC 16384
#define NSPLIT 8
#define MARGIN 0.02f      // >20x the (split + 7-bit packing) comparison error
#define TILE_BYTES 32768  // 64 codes x 128 dims x 2B x (hi+lo)
#define NTILES 32         // tiles per 2048-code slice

typedef __bf16 bf16x8 __attribute__((ext_vector_type(8)));
typedef unsigned short u16x8 __attribute__((ext_vector_type(8)));
typedef float f32x4 __attribute__((ext_vector_type(4)));

static __device__ __forceinline__ unsigned short f2bf(float f) {
    unsigned u = __float_as_uint(f);
    return (unsigned short)((u + 0x7FFFu + ((u >> 16) & 1u)) >> 16);
}
static __device__ __forceinline__ float bf2f(unsigned short u) {
    return __uint_as_float(((unsigned)u) << 16);
}
static __device__ __forceinline__ bf16x8 u2b(u16x8 u) {
    return __builtin_bit_cast(bf16x8, u);
}
static __device__ __forceinline__ void gl2lds(const void* g, void* l) {
    __builtin_amdgcn_global_load_lds(
        (const __attribute__((address_space(1))) unsigned int*)g,
        (__attribute__((address_space(3))) unsigned int*)l, 16, 0, 0);
}

// ---- codebook fp32 -> bf16 hi/lo, tile-image layout with chunk rotation ----
__global__ __launch_bounds__(512) void lfq_convert_cb(
    const float4* __restrict__ cb4, unsigned short* __restrict__ cbs)
{
    const unsigned i = blockIdx.x * 512 + threadIdx.x;   // 0..524287
    float4 v = cb4[i];
    const unsigned c    = i >> 5;
    const unsigned d0   = (i & 31u) << 2;
    const unsigned tile = c >> 6, r = c & 63u;
    const unsigned pos  = ((d0 >> 3) + r) & 15u;
    const unsigned base = tile * 16384u + r * 128u + pos * 8u + (d0 & 7u);
    ushort4 h, l;
    h.x = f2bf(v.x); l.x = f2bf(v.x - bf2f(h.x));
    h.y = f2bf(v.y); l.y = f2bf(v.y - bf2f(h.y));
    h.z = f2bf(v.z); l.z = f2bf(v.z - bf2f(h.z));
    h.w = f2bf(v.w); l.w = f2bf(v.w - bf2f(h.w));
    *(ushort4*)(cbs + base)        = h;
    *(ushort4*)(cbs + base + 8192) = l;
}

// round-3/4-validated exact fp32 dot (reads ORIGINAL fp32 codebook)
static __device__ __forceinline__ float exact_dot(
    const float4* __restrict__ xr4, const float* __restrict__ cf, int cidx)
{
    const float4* cr = (const float4*)(cf + (size_t)cidx * ND);
    float a0 = 0.f, a1 = 0.f, a2 = 0.f, a3 = 0.f;
#pragma unroll
    for (int i = 0; i < 32; i += 4) {
        float4 x0 = xr4[i+0], x1 = xr4[i+1], x2 = xr4[i+2], x3 = xr4[i+3];
        float4 c0 = cr[i+0],  c1 = cr[i+1],  c2 = cr[i+2],  c3 = cr[i+3];
        a0 += x0.x*c0.x + x0.y*c0.y + x0.z*c0.z + x0.w*c0.w;
        a1 += x1.x*c1.x + x1.y*c1.y + x1.z*c1.z + x1.w*c1.w;
        a2 += x2.x*c2.x + x2.y*c2.y + x2.z*c2.z + x2.w*c2.w;
        a3 += x3.x*c3.x + x3.y*c3.y + x3.z*c3.z + x3.w*c3.w;
    }
    return (a0 + a1) + (a2 + a3);
}

// ---- stage 1: grid 512 = 64 token-blocks(256 tok) x 8 splits (XCD-affine) ---
__global__ __launch_bounds__(512, 1) void lfq_stage1(
    const float* __restrict__ xf, const unsigned short* __restrict__ cbs,
    float* __restrict__ sb1, float* __restrict__ sb2,
    int* __restrict__ si1, int* __restrict__ si2)
{
    const int split = blockIdx.x & 7;
    const int tb    = blockIdx.x >> 3;
    const int t0    = tb * 256;
    const int tid   = threadIdx.x;
    const int w     = tid >> 6;       // wave id = token-group, 0..7
    const int lane  = tid & 63;
    const int n     = lane & 15;
    const int quad  = lane >> 4;

    __shared__ __attribute__((aligned(16))) unsigned char lds[2 * TILE_BYTES];

    // A fragments: tokens t0 + w*32 + tt*16 + n, tt=0..1; fp32 -> bf16 hi/lo.
    bf16x8 ah[2][4], al[2][4];
#pragma unroll
    for (int tt = 0; tt < 2; ++tt) {
        const float* xr = xf + (size_t)(t0 + w * 32 + tt * 16 + n) * ND + quad * 8;
#pragma unroll
        for (int kk = 0; kk < 4; ++kk) {
            float4 v0 = *(const float4*)(xr + kk * 32);
            float4 v1 = *(const float4*)(xr + kk * 32 + 4);
            u16x8 hu, lu;
            hu[0] = f2bf(v0.x); lu[0] = f2bf(v0.x - bf2f(hu[0]));
            hu[1] = f2bf(v0.y); lu[1] = f2bf(v0.y - bf2f(hu[1]));
            hu[2] = f2bf(v0.z); lu[2] = f2bf(v0.z - bf2f(hu[2]));
            hu[3] = f2bf(v0.w); lu[3] = f2bf(v0.w - bf2f(hu[3]));
            hu[4] = f2bf(v1.x); lu[4] = f2bf(v1.x - bf2f(hu[4]));
            hu[5] = f2bf(v1.y); lu[5] = f2bf(v1.y - bf2f(hu[5]));
            hu[6] = f2bf(v1.z); lu[6] = f2bf(v1.z - bf2f(hu[6]));
            hu[7] = f2bf(v1.w); lu[7] = f2bf(v1.w - bf2f(hu[7]));
            ah[tt][kk] = u2b(hu);
            al[tt][kk] = u2b(lu);
        }
    }

    float b1[2][4], b2[2][4];
#pragma unroll
    for (int tt = 0; tt < 2; ++tt)
#pragma unroll
        for (int r = 0; r < 4; ++r) { b1[tt][r] = -3.0e38f; b2[tt][r] = -3.0e38f; }

    const unsigned char* gtiles =
        (const unsigned char*)cbs + (size_t)(split * NTILES) * TILE_BYTES;
    const unsigned sgo  = (unsigned)(w * 1024 + lane * 16);
    const unsigned ldso = (unsigned)(w * 1024);   // wave-uniform LDS segment

    // stage tile 0 into buffer 0
#pragma unroll
    for (int rd = 0; rd < 4; ++rd)
        gl2lds(gtiles + rd * 8192 + sgo, &lds[rd * 8192 + ldso]);
    __syncthreads();

    for (int t = 0; t < NTILES; ++t) {
        const unsigned bufo = (unsigned)(t & 1) * TILE_BYTES;
        if (t < NTILES - 1) {      // async prefetch of next tile (other buffer)
            const unsigned char* g = gtiles + (size_t)(t + 1) * TILE_BYTES;
            const unsigned nbo = (unsigned)((t + 1) & 1) * TILE_BYTES;
#pragma unroll
            for (int rd = 0; rd < 4; ++rd)
                gl2lds(g + rd * 8192 + sgo, &lds[nbo + rd * 8192 + ldso]);
        }
#pragma unroll
        for (int s = 0; s < 4; ++s) {
            const int r = s * 16 + n;
            const unsigned rowh = bufo + (unsigned)r * 256;
            const unsigned rowl = rowh + 16384;
            const unsigned p0 = (unsigned)(quad + r) & 15u;
            const unsigned o0 = ((p0      ) & 15u) << 4;
            const unsigned o1 = ((p0 +  4u) & 15u) << 4;
            const unsigned o2 = ((p0 +  8u) & 15u) << 4;
            const unsigned o3 = ((p0 + 12u) & 15u) << 4;

            f32x4 a0 = {0.f,0.f,0.f,0.f}, a1v = {0.f,0.f,0.f,0.f};
            {   // hi fragments: ah*Bh and al*Bh (16 MFMAs)
                bf16x8 q0 = *(const bf16x8*)&lds[rowh + o0];
                bf16x8 q1 = *(const bf16x8*)&lds[rowh + o1];
                bf16x8 q2 = *(const bf16x8*)&lds[rowh + o2];
                bf16x8 q3 = *(const bf16x8*)&lds[rowh + o3];
                a0  = __builtin_amdgcn_mfma_f32_16x16x32_bf16(ah[0][0], q0, a0, 0,0,0);
                a0  = __builtin_amdgcn_mfma_f32_16x16x32_bf16(ah[0][1], q1, a0, 0,0,0);
                a0  = __builtin_amdgcn_mfma_f32_16x16x32_bf16(ah[0][2], q2, a0, 0,0,0);
                a0  = __builtin_amdgcn_mfma_f32_16x16x32_bf16(ah[0][3], q3, a0, 0,0,0);
                a0  = __builtin_amdgcn_mfma_f32_16x16x32_bf16(al[0][0], q0, a0, 0,0,0);
                a0  = __builtin_amdgcn_mfma_f32_16x16x32_bf16(al[0][1], q1, a0, 0,0,0);
                a0  = __builtin_amdgcn_mfma_f32_16x16x32_bf16(al[0][2], q2, a0, 0,0,0);
                a0  = __builtin_amdgcn_mfma_f32_16x16x32_bf16(al[0][3], q3, a0, 0,0,0);
                a1v = __builtin_amdgcn_mfma_f32_16x16x32_bf16(ah[1][0], q0, a1v, 0,0,0);
                a1v = __builtin_amdgcn_mfma_f32_16x16x32_bf16(ah[1][1], q1, a1v, 0,0,0);
                a1v = __builtin_amdgcn_mfma_f32_16x16x32_bf16(ah[1][2], q2, a1v, 0,0,0);
                a1v = __builtin_amdgcn_mfma_f32_16x16x32_bf16(ah[1][3], q3, a1v, 0,0,0);
                a1v = __builtin_amdgcn_mfma_f32_16x16x32_bf16(al[1][0], q0, a1v, 0,0,0);
                a1v = __builtin_amdgcn_mfma_f32_16x16x32_bf16(al[1][1], q1, a1v, 0,0,0);
                a1v = __builtin_amdgcn_mfma_f32_16x16x32_bf16(al[1][2], q2, a1v, 0,0,0);
                a1v = __builtin_amdgcn_mfma_f32_16x16x32_bf16(al[1][3], q3, a1v, 0,0,0);
            }
            {   // lo fragments: ah*Bl (8 MFMAs)
                bf16x8 q0 = *(const bf16x8*)&lds[rowl + o0];
                bf16x8 q1 = *(const bf16x8*)&lds[rowl + o1];
                bf16x8 q2 = *(const bf16x8*)&lds[rowl + o2];
                bf16x8 q3 = *(const bf16x8*)&lds[rowl + o3];
                a0  = __builtin_amdgcn_mfma_f32_16x16x32_bf16(ah[0][0], q0, a0, 0,0,0);
                a0  = __builtin_amdgcn_mfma_f32_16x16x32_bf16(ah[0][1], q1, a0, 0,0,0);
                a0  = __builtin_amdgcn_mfma_f32_16x16x32_bf16(ah[0][2], q2, a0, 0,0,0);
                a0  = __builtin_amdgcn_mfma_f32_16x16x32_bf16(ah[0][3], q3, a0, 0,0,0);
                a1v = __builtin_amdgcn_mfma_f32_16x16x32_bf16(ah[1][0], q0, a1v, 0,0,0);
                a1v = __builtin_amdgcn_mfma_f32_16x16x32_bf16(ah[1][1], q1, a1v, 0,0,0);
                a1v = __builtin_amdgcn_mfma_f32_16x16x32_bf16(ah[1][2], q2, a1v, 0,0,0);
                a1v = __builtin_amdgcn_mfma_f32_16x16x32_bf16(ah[1][3], q3, a1v, 0,0,0);
            }
            const unsigned pk = (unsigned)(127 - (t * 4 + s));
#pragma unroll
            for (int r4 = 0; r4 < 4; ++r4) {
                float p = __uint_as_float((__float_as_uint(a0[r4]) & 0xFFFFFF80u) | pk);
                b2[0][r4] = __builtin_amdgcn_fmed3f(p, b1[0][r4], b2[0][r4]);
                b1[0][r4] = fmaxf(p, b1[0][r4]);
                float p2 = __uint_as_float((__float_as_uint(a1v[r4]) & 0xFFFFFF80u) | pk);
                b2[1][r4] = __builtin_amdgcn_fmed3f(p2, b1[1][r4], b2[1][r4]);
                b1[1][r4] = fmaxf(p2, b1[1][r4]);
            }
        }
        __syncthreads();   // drains prefetch (vmcnt) + protects buffer swap
    }

    // unpack (score, code) and cross-lane top-2 merge over 16 code-lanes
    const int cb_base = split * (NC / NSPLIT);
    float v1[2][4], v2[2][4];
    int   c1[2][4], c2[2][4];
#pragma unroll
    for (int tt = 0; tt < 2; ++tt)
#pragma unroll
        for (int r = 0; r < 4; ++r) {
            int j1 = 127 - (int)(__float_as_uint(b1[tt][r]) & 127u);
            int j2 = 127 - (int)(__float_as_uint(b2[tt][r]) & 127u);
            v1[tt][r] = b1[tt][r]; c1[tt][r] = cb_base + j1 * 16 + n;
            v2[tt][r] = b2[tt][r]; c2[tt][r] = cb_base + j2 * 16 + n;
        }

#pragma unroll
    for (int tt = 0; tt < 2; ++tt)
#pragma unroll
        for (int r = 0; r < 4; ++r) {
#pragma unroll
            for (int off = 1; off < 16; off <<= 1) {
                float ob1 = __shfl_xor(v1[tt][r], off, 64);
                int   oi1 = __shfl_xor(c1[tt][r], off, 64);
                float ob2 = __shfl_xor(v2[tt][r], off, 64);
                int   oi2 = __shfl_xor(c2[tt][r], off, 64);
                bool gt = (ob1 > v1[tt][r]) ||
                          (ob1 == v1[tt][r] && oi1 < c1[tt][r]);
                float ls = gt ? v1[tt][r] : ob1;
                int   li = gt ? c1[tt][r] : oi1;
                float ws_ = gt ? ob2 : v2[tt][r];
                int   wi = gt ? oi2 : c2[tt][r];
                bool s2 = (ls > ws_) || (ls == ws_ && li < wi);
                v2[tt][r] = s2 ? ls : ws_;
                c2[tt][r] = s2 ? li : wi;
                v1[tt][r] = gt ? ob1 : v1[tt][r];
                c1[tt][r] = gt ? oi1 : c1[tt][r];
            }
        }

    // each wave owns its 32 tokens exclusively -> direct store, no LDS merge
    if (n == 0) {
#pragma unroll
        for (int tt = 0; tt < 2; ++tt)
#pragma unroll
            for (int r = 0; r < 4; ++r) {
                const int token = t0 + w * 32 + tt * 16 + quad * 4 + r;
                const size_t o = (size_t)split * NT + token;
                sb1[o] = v1[tt][r]; si1[o] = c1[tt][r];
                sb2[o] = v2[tt][r]; si2[o] = c2[tt][r];
            }
    }
}

// ------------- combine: merge 8 splits, exact-rescore margin band -------------
__global__ __launch_bounds__(256) void lfq_combine(
    const float* __restrict__ sb1, const float* __restrict__ sb2,
    const int* __restrict__ si1, const int* __restrict__ si2,
    const float* __restrict__ xf, const float* __restrict__ cf,
    float* __restrict__ out, int out_size)
{
    const int t = blockIdx.x * 256 + threadIdx.x;

    float v[16]; int id[16];
#pragma unroll
    for (int s = 0; s < NSPLIT; ++s) {
        const size_t o = (size_t)s * NT + t;
        v[2*s]   = sb1[o]; id[2*s]   = si1[o];
        v[2*s+1] = sb2[o]; id[2*s+1] = si2[o];
    }
    float A1 = v[0]; int I1 = id[0];
#pragma unroll
    for (int k = 1; k < 16; ++k)
        if (v[k] > A1 || (v[k] == A1 && id[k] < I1)) { A1 = v[k]; I1 = id[k]; }

    float4 xr4[32];
    const float4* xrow = (const float4*)(xf + (size_t)t * ND);
#pragma unroll
    for (int i = 0; i < 32; ++i) xr4[i] = xrow[i];

    float bs = -__builtin_inff(); int bi = 0; bool have = false;
#pragma unroll
    for (int k = 0; k < 16; ++k) {
        if (v[k] >= A1 - MARGIN) {
            float s = exact_dot(xr4, cf, id[k]);
            if (!have || s > bs || (s == bs && id[k] < bi)) { bs = s; bi = id[k]; have = true; }
        }
    }
    out[t] = (float)bi;
    if (t == 0 && out_size > NT) out[NT] = 0.0f;
}

// ------------- fallback: round-3 exact fp32 kernel (tiny ws) -------------
__global__ __launch_bounds__(512) void lfq_fp32_argmax(
    const float* __restrict__ xf, const float* __restrict__ cf,
    float* __restrict__ out, int out_size)
{
    const int tid = threadIdx.x;
    const int w   = tid >> 6;
    const int tok = tid & 63;
    const int t0  = blockIdx.x * 64;
    __shared__ float s_sc[8][64];
    __shared__ int   s_ix[8][64];

    float4 xr[32];
    const float4* xrow = (const float4*)(xf + (size_t)(t0 + tok) * ND);
#pragma unroll
    for (int i = 0; i < 32; ++i) xr[i] = xrow[i];

    float bs = -__builtin_inff();
    int   bi = 0;
    const int c_begin = w * (NC / 8);
    for (int c = c_begin; c < c_begin + NC / 8; ++c) {
        float s = exact_dot(xr, cf, c);
        if (s > bs) { bs = s; bi = c; }
    }
    s_sc[w][tok] = bs; s_ix[w][tok] = bi;
    __syncthreads();
    if (tid < 64) {
        float bsf = s_sc[0][tid]; int bif = s_ix[0][tid];
#pragma unroll
        for (int ww = 1; ww < 8; ++ww) {
            float s2 = s_sc[ww][tid]; int ii = s_ix[ww][tid];
            if (s2 > bsf || (s2 == bsf && ii < bif)) { bsf = s2; bif = ii; }
        }
        out[t0 + tid] = (float)bif;
    }
    if (blockIdx.x == 0 && tid == 0 && out_size > NT) out[NT] = 0.0f;
}

extern "C" void kernel_launch(void* const* d_in, const int* in_sizes, int n_in,
                              void* d_out, int out_size, void* d_ws, size_t ws_size,
                              hipStream_t stream) {
    const float* x  = (const float*)d_in[0];
    const float* cb = (const float*)d_in[1];
    float* out = (float*)d_out;

    // ws: cbs 8.39MB (swizzled tile images) | sb1/sb2/si1/si2 512KB each
    const size_t NCE = (size_t)NC * ND;          // 2,097,152 codebook elements
    const size_t NEED = NCE * 2 * 2 + (size_t)NT * NSPLIT * 4 * 4;
    if (ws_size >= NEED) {
        char* ws = (char*)d_ws;
        unsigned short* cbs = (unsigned short*)ws;
        char* sp = ws + NCE * 4;
        float* sb1 = (float*)sp;
        float* sb2 = (float*)(sp + (size_t)NT * NSPLIT * 4);
        int*   si1 = (int*)  (sp + (size_t)NT * NSPLIT * 8);
        int*   si2 = (int*)  (sp + (size_t)NT * NSPLIT * 12);

        lfq_convert_cb<<<dim3(1024), dim3(512), 0, stream>>>(
            (const float4*)cb, cbs);
        lfq_stage1<<<dim3((NT / 256) * NSPLIT), dim3(512), 0, stream>>>(
            x, cbs, sb1, sb2, si1, si2);
        lfq_combine<<<dim3(64), dim3(256), 0, stream>>>(
            sb1, sb2, si1, si2, x, cb, out, out_size);
    } else {
        lfq_fp32_argmax<<<dim3(NT / 64), dim3(512), 0, stream>>>(x, cb, out, out_size);
    }
}

// Round 12
// 255.904 us; speedup vs baseline: 41.2539x; 1.0073x over previous
//
#include <hip/hip_runtime.h>
#include <hip/hip_bf16.h>

// LFQ argmax, round 12: tt=4 per wave on the r11 LDS-shared structure.
// r11 decomposition: MFMA 94 us (floor 99, fixed by 3-term numerics) vs LDS
// 16384 b128-reads/CU x ~16cyc = 109 us -> LDS co-bottleneck. Doubling
// MFMA-per-LDS-read (48 per 8 reads) halves LDS time to ~55 us < MFMA.
// Block = 4 waves x 64 tokens (256 thr; dodges the 8-wave 128-VGPR allocator
// trap of r8/r9; r10 precedent: tt=4 fits at 152 VGPRs). Block covers 256
// tokens; B tile (64 codes hi+lo, 32 KB) LDS double-buffered, global_load_lds
// width=16; 2 blocks/CU (128 KB LDS). Combine: band-count shortcut (skip all
// exact dots when only the winner is within MARGIN — exactness guaranteed).
// Numerics (validated r6-r11): 3-term split-bf16, 7-bit j-pack top-2,
// per-split top-2, exact rescore of MARGIN band. Output float32[16385].
#define NT 16384
#define ND 128
#define NC 16384
#define NSPLIT 8
#define MARGIN 0.02f      // >20x the (split + 7-bit packing) comparison error
#define TILE_BYTES 32768  // 64 codes x 128 dims x 2B x (hi+lo)
#define NTILES 32         // tiles per 2048-code slice

typedef __bf16 bf16x8 __attribute__((ext_vector_type(8)));
typedef unsigned short u16x8 __attribute__((ext_vector_type(8)));
typedef float f32x4 __attribute__((ext_vector_type(4)));

static __device__ __forceinline__ unsigned short f2bf(float f) {
    unsigned u = __float_as_uint(f);
    return (unsigned short)((u + 0x7FFFu + ((u >> 16) & 1u)) >> 16);
}
static __device__ __forceinline__ float bf2f(unsigned short u) {
    return __uint_as_float(((unsigned)u) << 16);
}
static __device__ __forceinline__ bf16x8 u2b(u16x8 u) {
    return __builtin_bit_cast(bf16x8, u);
}
static __device__ __forceinline__ void gl2lds(const void* g, void* l) {
    __builtin_amdgcn_global_load_lds(
        (const __attribute__((address_space(1))) unsigned int*)g,
        (__attribute__((address_space(3))) unsigned int*)l, 16, 0, 0);
}

// ---- codebook fp32 -> bf16 hi/lo, tile-image layout with chunk rotation ----
__global__ __launch_bounds__(512) void lfq_convert_cb(
    const float4* __restrict__ cb4, unsigned short* __restrict__ cbs)
{
    const unsigned i = blockIdx.x * 512 + threadIdx.x;   // 0..524287
    float4 v = cb4[i];
    const unsigned c    = i >> 5;
    const unsigned d0   = (i & 31u) << 2;
    const unsigned tile = c >> 6, r = c & 63u;
    const unsigned pos  = ((d0 >> 3) + r) & 15u;
    const unsigned base = tile * 16384u + r * 128u + pos * 8u + (d0 & 7u);
    ushort4 h, l;
    h.x = f2bf(v.x); l.x = f2bf(v.x - bf2f(h.x));
    h.y = f2bf(v.y); l.y = f2bf(v.y - bf2f(h.y));
    h.z = f2bf(v.z); l.z = f2bf(v.z - bf2f(h.z));
    h.w = f2bf(v.w); l.w = f2bf(v.w - bf2f(h.w));
    *(ushort4*)(cbs + base)        = h;
    *(ushort4*)(cbs + base + 8192) = l;
}

// round-3/4-validated exact fp32 dot (reads ORIGINAL fp32 codebook)
static __device__ __forceinline__ float exact_dot(
    const float4* __restrict__ xr4, const float* __restrict__ cf, int cidx)
{
    const float4* cr = (const float4*)(cf + (size_t)cidx * ND);
    float a0 = 0.f, a1 = 0.f, a2 = 0.f, a3 = 0.f;
#pragma unroll
    for (int i = 0; i < 32; i += 4) {
        float4 x0 = xr4[i+0], x1 = xr4[i+1], x2 = xr4[i+2], x3 = xr4[i+3];
        float4 c0 = cr[i+0],  c1 = cr[i+1],  c2 = cr[i+2],  c3 = cr[i+3];
        a0 += x0.x*c0.x + x0.y*c0.y + x0.z*c0.z + x0.w*c0.w;
        a1 += x1.x*c1.x + x1.y*c1.y + x1.z*c1.z + x1.w*c1.w;
        a2 += x2.x*c2.x + x2.y*c2.y + x2.z*c2.z + x2.w*c2.w;
        a3 += x3.x*c3.x + x3.y*c3.y + x3.z*c3.z + x3.w*c3.w;
    }
    return (a0 + a1) + (a2 + a3);
}

// ---- stage 1: grid 512 = 64 token-blocks(256 tok) x 8 splits (XCD-affine) ---
// Block: 256 threads = 4 waves; wave w covers tokens t0+w*64..+63 (tt=4),
// all waves sweep the 2048-code slice from LDS.
__global__ __launch_bounds__(256, 1) void lfq_stage1(
    const float* __restrict__ xf, const unsigned short* __restrict__ cbs,
    float* __restrict__ sb1, float* __restrict__ sb2,
    int* __restrict__ si1, int* __restrict__ si2)
{
    const int split = blockIdx.x & 7;
    const int tb    = blockIdx.x >> 3;
    const int t0    = tb * 256;
    const int tid   = threadIdx.x;
    const int w     = tid >> 6;       // wave id = token-group, 0..3
    const int lane  = tid & 63;
    const int n     = lane & 15;
    const int quad  = lane >> 4;

    __shared__ __attribute__((aligned(16))) unsigned char lds[2 * TILE_BYTES];

    // A fragments: tokens t0 + w*64 + tt*16 + n, tt=0..3; fp32 -> bf16 hi/lo.
    bf16x8 ah[4][4], al[4][4];
#pragma unroll
    for (int tt = 0; tt < 4; ++tt) {
        const float* xr = xf + (size_t)(t0 + w * 64 + tt * 16 + n) * ND + quad * 8;
#pragma unroll
        for (int kk = 0; kk < 4; ++kk) {
            float4 v0 = *(const float4*)(xr + kk * 32);
            float4 v1 = *(const float4*)(xr + kk * 32 + 4);
            u16x8 hu, lu;
            hu[0] = f2bf(v0.x); lu[0] = f2bf(v0.x - bf2f(hu[0]));
            hu[1] = f2bf(v0.y); lu[1] = f2bf(v0.y - bf2f(hu[1]));
            hu[2] = f2bf(v0.z); lu[2] = f2bf(v0.z - bf2f(hu[2]));
            hu[3] = f2bf(v0.w); lu[3] = f2bf(v0.w - bf2f(hu[3]));
            hu[4] = f2bf(v1.x); lu[4] = f2bf(v1.x - bf2f(hu[4]));
            hu[5] = f2bf(v1.y); lu[5] = f2bf(v1.y - bf2f(hu[5]));
            hu[6] = f2bf(v1.z); lu[6] = f2bf(v1.z - bf2f(hu[6]));
            hu[7] = f2bf(v1.w); lu[7] = f2bf(v1.w - bf2f(hu[7]));
            ah[tt][kk] = u2b(hu);
            al[tt][kk] = u2b(lu);
        }
    }

    float b1[4][4], b2[4][4];
#pragma unroll
    for (int tt = 0; tt < 4; ++tt)
#pragma unroll
        for (int r = 0; r < 4; ++r) { b1[tt][r] = -3.0e38f; b2[tt][r] = -3.0e38f; }

    const unsigned char* gtiles =
        (const unsigned char*)cbs + (size_t)(split * NTILES) * TILE_BYTES;
    const unsigned sgo  = (unsigned)(w * 1024 + lane * 16); // global per-lane
    const unsigned ldso = (unsigned)(w * 1024);             // wave-uniform LDS

    // stage tile 0 into buffer 0 (8 rounds x 4 KB)
#pragma unroll
    for (int rd = 0; rd < 8; ++rd)
        gl2lds(gtiles + rd * 4096 + sgo, &lds[rd * 4096 + ldso]);
    __syncthreads();

    for (int t = 0; t < NTILES; ++t) {
        const unsigned bufo = (unsigned)(t & 1) * TILE_BYTES;
        if (t < NTILES - 1) {      // async prefetch of next tile (other buffer)
            const unsigned char* g = gtiles + (size_t)(t + 1) * TILE_BYTES;
            const unsigned nbo = (unsigned)((t + 1) & 1) * TILE_BYTES;
#pragma unroll
            for (int rd = 0; rd < 8; ++rd)
                gl2lds(g + rd * 4096 + sgo, &lds[nbo + rd * 4096 + ldso]);
        }
#pragma unroll
        for (int s = 0; s < 4; ++s) {
            const int r = s * 16 + n;
            const unsigned rowh = bufo + (unsigned)r * 256;
            const unsigned rowl = rowh + 16384;
            const unsigned p0 = (unsigned)(quad + r) & 15u;
            const unsigned o0 = ((p0      ) & 15u) << 4;
            const unsigned o1 = ((p0 +  4u) & 15u) << 4;
            const unsigned o2 = ((p0 +  8u) & 15u) << 4;
            const unsigned o3 = ((p0 + 12u) & 15u) << 4;

            f32x4 a0 = {0.f,0.f,0.f,0.f}, a1 = {0.f,0.f,0.f,0.f};
            f32x4 a2 = {0.f,0.f,0.f,0.f}, a3 = {0.f,0.f,0.f,0.f};
            {   // hi B fragments: ah*Bh + al*Bh (32 MFMAs)
                bf16x8 q0 = *(const bf16x8*)&lds[rowh + o0];
                bf16x8 q1 = *(const bf16x8*)&lds[rowh + o1];
                bf16x8 q2 = *(const bf16x8*)&lds[rowh + o2];
                bf16x8 q3 = *(const bf16x8*)&lds[rowh + o3];
                a0 = __builtin_amdgcn_mfma_f32_16x16x32_bf16(ah[0][0], q0, a0, 0,0,0);
                a1 = __builtin_amdgcn_mfma_f32_16x16x32_bf16(ah[1][0], q0, a1, 0,0,0);
                a2 = __builtin_amdgcn_mfma_f32_16x16x32_bf16(ah[2][0], q0, a2, 0,0,0);
                a3 = __builtin_amdgcn_mfma_f32_16x16x32_bf16(ah[3][0], q0, a3, 0,0,0);
                a0 = __builtin_amdgcn_mfma_f32_16x16x32_bf16(ah[0][1], q1, a0, 0,0,0);
                a1 = __builtin_amdgcn_mfma_f32_16x16x32_bf16(ah[1][1], q1, a1, 0,0,0);
                a2 = __builtin_amdgcn_mfma_f32_16x16x32_bf16(ah[2][1], q1, a2, 0,0,0);
                a3 = __builtin_amdgcn_mfma_f32_16x16x32_bf16(ah[3][1], q1, a3, 0,0,0);
                a0 = __builtin_amdgcn_mfma_f32_16x16x32_bf16(ah[0][2], q2, a0, 0,0,0);
                a1 = __builtin_amdgcn_mfma_f32_16x16x32_bf16(ah[1][2], q2, a1, 0,0,0);
                a2 = __builtin_amdgcn_mfma_f32_16x16x32_bf16(ah[2][2], q2, a2, 0,0,0);
                a3 = __builtin_amdgcn_mfma_f32_16x16x32_bf16(ah[3][2], q2, a3, 0,0,0);
                a0 = __builtin_amdgcn_mfma_f32_16x16x32_bf16(ah[0][3], q3, a0, 0,0,0);
                a1 = __builtin_amdgcn_mfma_f32_16x16x32_bf16(ah[1][3], q3, a1, 0,0,0);
                a2 = __builtin_amdgcn_mfma_f32_16x16x32_bf16(ah[2][3], q3, a2, 0,0,0);
                a3 = __builtin_amdgcn_mfma_f32_16x16x32_bf16(ah[3][3], q3, a3, 0,0,0);
                a0 = __builtin_amdgcn_mfma_f32_16x16x32_bf16(al[0][0], q0, a0, 0,0,0);
                a1 = __builtin_amdgcn_mfma_f32_16x16x32_bf16(al[1][0], q0, a1, 0,0,0);
                a2 = __builtin_amdgcn_mfma_f32_16x16x32_bf16(al[2][0], q0, a2, 0,0,0);
                a3 = __builtin_amdgcn_mfma_f32_16x16x32_bf16(al[3][0], q0, a3, 0,0,0);
                a0 = __builtin_amdgcn_mfma_f32_16x16x32_bf16(al[0][1], q1, a0, 0,0,0);
                a1 = __builtin_amdgcn_mfma_f32_16x16x32_bf16(al[1][1], q1, a1, 0,0,0);
                a2 = __builtin_amdgcn_mfma_f32_16x16x32_bf16(al[2][1], q1, a2, 0,0,0);
                a3 = __builtin_amdgcn_mfma_f32_16x16x32_bf16(al[3][1], q1, a3, 0,0,0);
                a0 = __builtin_amdgcn_mfma_f32_16x16x32_bf16(al[0][2], q2, a0, 0,0,0);
                a1 = __builtin_amdgcn_mfma_f32_16x16x32_bf16(al[1][2], q2, a1, 0,0,0);
                a2 = __builtin_amdgcn_mfma_f32_16x16x32_bf16(al[2][2], q2, a2, 0,0,0);
                a3 = __builtin_amdgcn_mfma_f32_16x16x32_bf16(al[3][2], q2, a3, 0,0,0);
                a0 = __builtin_amdgcn_mfma_f32_16x16x32_bf16(al[0][3], q3, a0, 0,0,0);
                a1 = __builtin_amdgcn_mfma_f32_16x16x32_bf16(al[1][3], q3, a1, 0,0,0);
                a2 = __builtin_amdgcn_mfma_f32_16x16x32_bf16(al[2][3], q3, a2, 0,0,0);
                a3 = __builtin_amdgcn_mfma_f32_16x16x32_bf16(al[3][3], q3, a3, 0,0,0);
            }
            {   // lo B fragments: ah*Bl (16 MFMAs)
                bf16x8 q0 = *(const bf16x8*)&lds[rowl + o0];
                bf16x8 q1 = *(const bf16x8*)&lds[rowl + o1];
                bf16x8 q2 = *(const bf16x8*)&lds[rowl + o2];
                bf16x8 q3 = *(const bf16x8*)&lds[rowl + o3];
                a0 = __builtin_amdgcn_mfma_f32_16x16x32_bf16(ah[0][0], q0, a0, 0,0,0);
                a1 = __builtin_amdgcn_mfma_f32_16x16x32_bf16(ah[1][0], q0, a1, 0,0,0);
                a2 = __builtin_amdgcn_mfma_f32_16x16x32_bf16(ah[2][0], q0, a2, 0,0,0);
                a3 = __builtin_amdgcn_mfma_f32_16x16x32_bf16(ah[3][0], q0, a3, 0,0,0);
                a0 = __builtin_amdgcn_mfma_f32_16x16x32_bf16(ah[0][1], q1, a0, 0,0,0);
                a1 = __builtin_amdgcn_mfma_f32_16x16x32_bf16(ah[1][1], q1, a1, 0,0,0);
                a2 = __builtin_amdgcn_mfma_f32_16x16x32_bf16(ah[2][1], q1, a2, 0,0,0);
                a3 = __builtin_amdgcn_mfma_f32_16x16x32_bf16(ah[3][1], q1, a3, 0,0,0);
                a0 = __builtin_amdgcn_mfma_f32_16x16x32_bf16(ah[0][2], q2, a0, 0,0,0);
                a1 = __builtin_amdgcn_mfma_f32_16x16x32_bf16(ah[1][2], q2, a1, 0,0,0);
                a2 = __builtin_amdgcn_mfma_f32_16x16x32_bf16(ah[2][2], q2, a2, 0,0,0);
                a3 = __builtin_amdgcn_mfma_f32_16x16x32_bf16(ah[3][2], q2, a3, 0,0,0);
                a0 = __builtin_amdgcn_mfma_f32_16x16x32_bf16(ah[0][3], q3, a0, 0,0,0);
                a1 = __builtin_amdgcn_mfma_f32_16x16x32_bf16(ah[1][3], q3, a1, 0,0,0);
                a2 = __builtin_amdgcn_mfma_f32_16x16x32_bf16(ah[2][3], q3, a2, 0,0,0);
                a3 = __builtin_amdgcn_mfma_f32_16x16x32_bf16(ah[3][3], q3, a3, 0,0,0);
            }
            const unsigned pk = (unsigned)(127 - (t * 4 + s));
#pragma unroll
            for (int r4 = 0; r4 < 4; ++r4) {
                float p0v = __uint_as_float((__float_as_uint(a0[r4]) & 0xFFFFFF80u) | pk);
                b2[0][r4] = __builtin_amdgcn_fmed3f(p0v, b1[0][r4], b2[0][r4]);
                b1[0][r4] = fmaxf(p0v, b1[0][r4]);
                float p1v = __uint_as_float((__float_as_uint(a1[r4]) & 0xFFFFFF80u) | pk);
                b2[1][r4] = __builtin_amdgcn_fmed3f(p1v, b1[1][r4], b2[1][r4]);
                b1[1][r4] = fmaxf(p1v, b1[1][r4]);
                float p2v = __uint_as_float((__float_as_uint(a2[r4]) & 0xFFFFFF80u) | pk);
                b2[2][r4] = __builtin_amdgcn_fmed3f(p2v, b1[2][r4], b2[2][r4]);
                b1[2][r4] = fmaxf(p2v, b1[2][r4]);
                float p3v = __uint_as_float((__float_as_uint(a3[r4]) & 0xFFFFFF80u) | pk);
                b2[3][r4] = __builtin_amdgcn_fmed3f(p3v, b1[3][r4], b2[3][r4]);
                b1[3][r4] = fmaxf(p3v, b1[3][r4]);
            }
        }
        __syncthreads();   // drains prefetch (vmcnt) + protects buffer swap
    }

    // unpack (score, code) and cross-lane top-2 merge over 16 code-lanes
    const int cb_base = split * (NC / NSPLIT);
    float v1[4][4], v2[4][4];
    int   c1[4][4], c2[4][4];
#pragma unroll
    for (int tt = 0; tt < 4; ++tt)
#pragma unroll
        for (int r = 0; r < 4; ++r) {
            int j1 = 127 - (int)(__float_as_uint(b1[tt][r]) & 127u);
            int j2 = 127 - (int)(__float_as_uint(b2[tt][r]) & 127u);
            v1[tt][r] = b1[tt][r]; c1[tt][r] = cb_base + j1 * 16 + n;
            v2[tt][r] = b2[tt][r]; c2[tt][r] = cb_base + j2 * 16 + n;
        }

#pragma unroll
    for (int tt = 0; tt < 4; ++tt)
#pragma unroll
        for (int r = 0; r < 4; ++r) {
#pragma unroll
            for (int off = 1; off < 16; off <<= 1) {
                float ob1 = __shfl_xor(v1[tt][r], off, 64);
                int   oi1 = __shfl_xor(c1[tt][r], off, 64);
                float ob2 = __shfl_xor(v2[tt][r], off, 64);
                int   oi2 = __shfl_xor(c2[tt][r], off, 64);
                bool gt = (ob1 > v1[tt][r]) ||
                          (ob1 == v1[tt][r] && oi1 < c1[tt][r]);
                float ls = gt ? v1[tt][r] : ob1;
                int   li = gt ? c1[tt][r] : oi1;
                float ws_ = gt ? ob2 : v2[tt][r];
                int   wi = gt ? oi2 : c2[tt][r];
                bool s2 = (ls > ws_) || (ls == ws_ && li < wi);
                v2[tt][r] = s2 ? ls : ws_;
                c2[tt][r] = s2 ? li : wi;
                v1[tt][r] = gt ? ob1 : v1[tt][r];
                c1[tt][r] = gt ? oi1 : c1[tt][r];
            }
        }

    // each wave owns its 64 tokens exclusively -> direct store, no LDS merge
    if (n == 0) {
#pragma unroll
        for (int tt = 0; tt < 4; ++tt)
#pragma unroll
            for (int r = 0; r < 4; ++r) {
                const int token = t0 + w * 64 + tt * 16 + quad * 4 + r;
                const size_t o = (size_t)split * NT + token;
                sb1[o] = v1[tt][r]; si1[o] = c1[tt][r];
                sb2[o] = v2[tt][r]; si2[o] = c2[tt][r];
            }
    }
}

// ------------- combine: merge 8 splits, exact-rescore margin band -------------
__global__ __launch_bounds__(256) void lfq_combine(
    const float* __restrict__ sb1, const float* __restrict__ sb2,
    const int* __restrict__ si1, const int* __restrict__ si2,
    const float* __restrict__ xf, const float* __restrict__ cf,
    float* __restrict__ out, int out_size)
{
    const int t = blockIdx.x * 256 + threadIdx.x;

    float v[16]; int id[16];
#pragma unroll
    for (int s = 0; s < NSPLIT; ++s) {
        const size_t o = (size_t)s * NT + t;
        v[2*s]   = sb1[o]; id[2*s]   = si1[o];
        v[2*s+1] = sb2[o]; id[2*s+1] = si2[o];
    }
    float A1 = v[0]; int I1 = id[0];
#pragma unroll
    for (int k = 1; k < 16; ++k)
        if (v[k] > A1 || (v[k] == A1 && id[k] < I1)) { A1 = v[k]; I1 = id[k]; }

    // band-count shortcut: if only the winner is within MARGIN, the approx
    // argmax is exact (all others are > MARGIN below in approx => below in
    // exact, since |approx - exact| << MARGIN/2 per score).
    int cnt = 0;
#pragma unroll
    for (int k = 0; k < 16; ++k) cnt += (v[k] >= A1 - MARGIN) ? 1 : 0;

    int bi = I1;
    if (cnt > 1) {
        float4 xr4[32];
        const float4* xrow = (const float4*)(xf + (size_t)t * ND);
#pragma unroll
        for (int i = 0; i < 32; ++i) xr4[i] = xrow[i];
        float bs = -__builtin_inff(); bool have = false; bi = 0;
#pragma unroll
        for (int k = 0; k < 16; ++k) {
            if (v[k] >= A1 - MARGIN) {
                float s = exact_dot(xr4, cf, id[k]);
                if (!have || s > bs || (s == bs && id[k] < bi)) { bs = s; bi = id[k]; have = true; }
            }
        }
    }
    out[t] = (float)bi;
    if (t == 0 && out_size > NT) out[NT] = 0.0f;
}

// ------------- fallback: round-3 exact fp32 kernel (tiny ws) -------------
__global__ __launch_bounds__(512) void lfq_fp32_argmax(
    const float* __restrict__ xf, const float* __restrict__ cf,
    float* __restrict__ out, int out_size)
{
    const int tid = threadIdx.x;
    const int w   = tid >> 6;
    const int tok = tid & 63;
    const int t0  = blockIdx.x * 64;
    __shared__ float s_sc[8][64];
    __shared__ int   s_ix[8][64];

    float4 xr[32];
    const float4* xrow = (const float4*)(xf + (size_t)(t0 + tok) * ND);
#pragma unroll
    for (int i = 0; i < 32; ++i) xr[i] = xrow[i];

    float bs = -__builtin_inff();
    int   bi = 0;
    const int c_begin = w * (NC / 8);
    for (int c = c_begin; c < c_begin + NC / 8; ++c) {
        float s = exact_dot(xr, cf, c);
        if (s > bs) { bs = s; bi = c; }
    }
    s_sc[w][tok] = bs; s_ix[w][tok] = bi;
    __syncthreads();
    if (tid < 64) {
        float bsf = s_sc[0][tid]; int bif = s_ix[0][tid];
#pragma unroll
        for (int ww = 1; ww < 8; ++ww) {
            float s2 = s_sc[ww][tid]; int ii = s_ix[ww][tid];
            if (s2 > bsf || (s2 == bsf && ii < bif)) { bsf = s2; bif = ii; }
        }
        out[t0 + tid] = (float)bif;
    }
    if (blockIdx.x == 0 && tid == 0 && out_size > NT) out[NT] = 0.0f;
}

extern "C" void kernel_launch(void* const* d_in, const int* in_sizes, int n_in,
                              void* d_out, int out_size, void* d_ws, size_t ws_size,
                              hipStream_t stream) {
    const float* x  = (const float*)d_in[0];
    const float* cb = (const float*)d_in[1];
    float* out = (float*)d_out;

    // ws: cbs 8.39MB (swizzled tile images) | sb1/sb2/si1/si2 512KB each
    const size_t NCE = (size_t)NC * ND;          // 2,097,152 codebook elements
    const size_t NEED = NCE * 2 * 2 + (size_t)NT * NSPLIT * 4 * 4;
    if (ws_size >= NEED) {
        char* ws = (char*)d_ws;
        unsigned short* cbs = (unsigned short*)ws;
        char* sp = ws + NCE * 4;
        float* sb1 = (float*)sp;
        float* sb2 = (float*)(sp + (size_t)NT * NSPLIT * 4);
        int*   si1 = (int*)  (sp + (size_t)NT * NSPLIT * 8);
        int*   si2 = (int*)  (sp + (size_t)NT * NSPLIT * 12);

        lfq_convert_cb<<<dim3(1024), dim3(512), 0, stream>>>(
            (const float4*)cb, cbs);
        lfq_stage1<<<dim3((NT / 256) * NSPLIT), dim3(256), 0, stream>>>(
            x, cbs, sb1, sb2, si1, si2);
        lfq_combine<<<dim3(64), dim3(256), 0, stream>>>(
            sb1, sb2, si1, si2, x, cb, out, out_size);
    } else {
        lfq_fp32_argmax<<<dim3(NT / 64), dim3(512), 0, stream>>>(x, cb, out, out_size);
    }
}